// Round 1
// baseline (8128.501 us; speedup 1.0000x reference)
//
#include <hip/hip_runtime.h>

#define NE 524288
#define NN 32768

#define F4(p) (*(const float4*)(p))

__device__ __forceinline__ float sigmoidf_(float v) { return 1.f / (1.f + expf(-v)); }

__device__ __forceinline__ void ld32(float* xr, const float* p) {
#pragma unroll
  for (int i = 0; i < 32; i += 4) {
    float4 v = F4(&p[i]);
    xr[i] = v.x; xr[i+1] = v.y; xr[i+2] = v.z; xr[i+3] = v.w;
  }
}

__device__ __forceinline__ float dot32r(const float* __restrict__ w, const float* xr) {
  float s = 0.f;
#pragma unroll
  for (int i = 0; i < 32; i += 4) {
    float4 ww = F4(&w[i]);
    s = fmaf(xr[i],   ww.x, s);
    s = fmaf(xr[i+1], ww.y, s);
    s = fmaf(xr[i+2], ww.z, s);
    s = fmaf(xr[i+3], ww.w, s);
  }
  return s;
}

// ---------------- embedding: x = x_atoms @ emb_W + emb_b ----------------
__global__ __launch_bounds__(128) void embed_kernel(
    const float* __restrict__ xa, const float* __restrict__ W,
    const float* __restrict__ b, float* __restrict__ x)
{
  __shared__ float a[64];
  const int n = blockIdx.x, t = threadIdx.x;
  if (t < 64) a[t] = xa[n*64 + t];
  __syncthreads();
  float s = b[t];
#pragma unroll 8
  for (int f = 0; f < 64; ++f) s = fmaf(a[f], W[f*128 + t], s);
  x[n*128 + t] = s;
}

// ---------------- distance features + in-degree counts ----------------
__global__ __launch_bounds__(256) void dist_cnt_kernel(
    const float* __restrict__ pos, const int* __restrict__ ei,
    float* __restrict__ df, float* __restrict__ cntf)
{
  const int e = blockIdx.x*256 + threadIdx.x;
  const int s = ei[e];        // edge_index[0] = src
  const int d = ei[NE + e];   // edge_index[1] = dst
  float dx = pos[d*3+0] - pos[s*3+0];
  float dy = pos[d*3+1] - pos[s*3+1];
  float dz = pos[d*3+2] - pos[s*3+2];
  float dist = sqrtf(dx*dx + dy*dy + dz*dz + 1e-12f);
  df[e*3+0] = dist;
  df[e*3+1] = 1.f/(1.f + dist);
  df[e*3+2] = expf(-dist);
  atomicAdd(&cntf[d], 1.f);
}

// ---------------- per-edge message MLP + scatter-add ----------------
// 32 edges per block, 128 threads. Input tile staged TRANSPOSED in LDS:
// in_t[k][e] (k=0..127 x[dst], 128..255 x[src], 256..258 dist_feat), row pad 36.
// Register tile per thread: 4 edges x 8 hidden. Inner loop: 1 ds_read_b128 +
// 2 global float4 (W, L2-hot) per 32 FMAs.
__global__ __launch_bounds__(128) void layer_kernel(
    const float* __restrict__ x, const float* __restrict__ df,
    const int* __restrict__ ei,
    const float* __restrict__ W1, const float* __restrict__ b1,
    const float* __restrict__ W2, const float* __restrict__ b2,
    float* __restrict__ acc)
{
  __shared__ float smem[259*36];
  const int tid = threadIdx.x;
  const int e0base = blockIdx.x * 32;
  const int* srcI = ei;
  const int* dstI = ei + NE;

  // staging: idx -> (e,c) interleaved so LDS-write bank = (4c+e)%32 is 2-way max
  for (int idx = tid; idx < 4096; idx += 128) {
    const int c = (idx & 15) | (((idx >> 6) & 7) << 4);
    const int e = ((idx >> 4) & 3) | (((idx >> 9) & 7) << 2);
    const int dd = dstI[e0base + e];
    const int ss = srcI[e0base + e];
    smem[c*36 + e]       = x[dd*128 + c];
    smem[(128+c)*36 + e] = x[ss*128 + c];
  }
  if (tid < 96) {
    const int e = tid / 3;
    const int j = tid - e*3;
    smem[(256+j)*36 + e] = df[e0base*3 + tid];
  }
  __syncthreads();

  const int eg = tid & 7, hg = tid >> 3;
  const int e0 = eg*4, h0 = hg*8;

  float hacc[4][8];
#pragma unroll
  for (int j = 0; j < 4; ++j)
#pragma unroll
    for (int i = 0; i < 8; ++i) hacc[j][i] = 0.f;

  for (int k = 0; k < 259; ++k) {
    const float4 a4 = F4(&smem[k*36 + e0]);
    const float4 w0 = F4(&W1[k*128 + h0]);
    const float4 w1 = F4(&W1[k*128 + h0 + 4]);
    const float av[4] = {a4.x, a4.y, a4.z, a4.w};
    const float wv[8] = {w0.x, w0.y, w0.z, w0.w, w1.x, w1.y, w1.z, w1.w};
#pragma unroll
    for (int j = 0; j < 4; ++j)
#pragma unroll
      for (int i = 0; i < 8; ++i)
        hacc[j][i] = fmaf(av[j], wv[i], hacc[j][i]);
  }
  __syncthreads();

  // bias + relu, write hid transposed hid_t[h][e] (aliases smem after barrier)
#pragma unroll
  for (int i = 0; i < 8; ++i) {
    const float bi = b1[h0 + i];
#pragma unroll
    for (int j = 0; j < 4; ++j)
      smem[(h0+i)*36 + e0 + j] = fmaxf(hacc[j][i] + bi, 0.f);
  }
  __syncthreads();

  float oacc[4][8];
#pragma unroll
  for (int j = 0; j < 4; ++j)
#pragma unroll
    for (int i = 0; i < 8; ++i) oacc[j][i] = 0.f;

  for (int h = 0; h < 128; ++h) {
    const float4 a4 = F4(&smem[h*36 + e0]);
    const float4 w0 = F4(&W2[h*128 + h0]);
    const float4 w1 = F4(&W2[h*128 + h0 + 4]);
    const float av[4] = {a4.x, a4.y, a4.z, a4.w};
    const float wv[8] = {w0.x, w0.y, w0.z, w0.w, w1.x, w1.y, w1.z, w1.w};
#pragma unroll
    for (int j = 0; j < 4; ++j)
#pragma unroll
      for (int i = 0; i < 8; ++i)
        oacc[j][i] = fmaf(av[j], wv[i], oacc[j][i]);
  }

#pragma unroll
  for (int j = 0; j < 4; ++j) {
    const int dd = dstI[e0base + e0 + j];
    float* dp = acc + dd*128 + h0;
#pragma unroll
    for (int i = 0; i < 8; ++i)
      atomicAdd(dp + i, oacc[j][i] + b2[h0 + i]);
  }
}

// ---------------- mean-agg + residual + layernorm (also re-zeros acc) ----------------
__global__ __launch_bounds__(64) void node_update_kernel(
    float* __restrict__ x, float* __restrict__ acc, const float* __restrict__ cntf,
    const float* __restrict__ g, const float* __restrict__ bb)
{
  const int n = blockIdx.x, t = threadIdx.x;
  const int base = n*128;
  const float rc = 1.f / fmaxf(cntf[n], 1.f);
  float v0 = acc[base + t]      * rc + x[base + t];
  float v1 = acc[base + 64 + t] * rc + x[base + 64 + t];
  acc[base + t] = 0.f;
  acc[base + 64 + t] = 0.f;
  float s = v0 + v1;
#pragma unroll
  for (int o = 1; o < 64; o <<= 1) s += __shfl_xor(s, o);
  const float mu = s * (1.f/128.f);
  const float d0 = v0 - mu, d1 = v1 - mu;
  float q = d0*d0 + d1*d1;
#pragma unroll
  for (int o = 1; o < 64; o <<= 1) q += __shfl_xor(q, o);
  const float rstd = rsqrtf(q*(1.f/128.f) + 1e-5f);
  x[base + t]      = d0*rstd*g[t]    + bb[t];
  x[base + 64 + t] = d1*rstd*g[t+64] + bb[t+64];
}

// ---------------- per-molecule MHA + pooling + proj ----------------
__global__ __launch_bounds__(128) void mol_kernel(
    const float* __restrict__ x,
    const float* __restrict__ win, const float* __restrict__ bin,
    const float* __restrict__ wout, const float* __restrict__ bout,
    const float* __restrict__ pW, const float* __restrict__ pb,
    float* __restrict__ expl, float* __restrict__ lrn)
{
  __shared__ float sx[4096];
  __shared__ float sqkv[12288];
  __shared__ float aw_l[32];
  __shared__ float spool[512];
  const int tid = threadIdx.x;
  const int b = blockIdx.x;

  for (int i = tid; i < 4096; i += 128) sx[i] = x[b*4096 + i];
  __syncthreads();

  { // qkv = xm @ win.T + bin  (thread = (row a, quad of k-range))
    const int a = tid >> 2, q4 = tid & 3;
    float xr[32];
    ld32(xr, &sx[a*128 + q4*32]);
    for (int c = 0; c < 384; ++c) {
      float s = dot32r(&win[c*128 + q4*32], xr);
      s += __shfl_xor(s, 1);
      s += __shfl_xor(s, 2);
      if (q4 == 0) sqkv[(c >> 7)*4096 + a*128 + (c & 127)] = s + bin[c];
    }
  }
  __syncthreads();

  { // per-head attention; thread = (head h, query row qr)
    const int h = tid >> 5, qr = tid & 31;
    const float* sq = sqkv;
    const float* sk = sqkv + 4096;
    const float* sv = sqkv + 8192;
    float qreg[32];
    ld32(qreg, &sq[qr*128 + h*32]);
    float sc[32];
#pragma unroll
    for (int k = 0; k < 32; ++k)
      sc[k] = dot32r(&sk[k*128 + h*32], qreg) * 0.17677669529663687f;
    float mx = sc[0];
#pragma unroll
    for (int k = 1; k < 32; ++k) mx = fmaxf(mx, sc[k]);
    float se = 0.f;
#pragma unroll
    for (int k = 0; k < 32; ++k) { sc[k] = expf(sc[k] - mx); se += sc[k]; }
    const float inv = 1.f / se;
    float od[32];
#pragma unroll
    for (int i = 0; i < 32; ++i) od[i] = 0.f;
#pragma unroll
    for (int k = 0; k < 32; ++k) {
      const float w = sc[k] * inv;
      const float* vr = &sv[k*128 + h*32];
#pragma unroll
      for (int i = 0; i < 32; i += 4) {
        float4 v = F4(&vr[i]);
        od[i]   = fmaf(w, v.x, od[i]);
        od[i+1] = fmaf(w, v.y, od[i+1]);
        od[i+2] = fmaf(w, v.z, od[i+2]);
        od[i+3] = fmaf(w, v.w, od[i+3]);
      }
    }
    __syncthreads();  // all reads of sq done -> safe to overwrite with o
#pragma unroll
    for (int i = 0; i < 32; i += 4)
      *(float4*)&sqkv[qr*128 + h*32 + i] = make_float4(od[i], od[i+1], od[i+2], od[i+3]);
  }
  __syncthreads();

  { // attended = o @ wout.T + bout  -> satt region (old sk)
    const int a = tid >> 2, q4 = tid & 3;
    float orr[32];
    ld32(orr, &sqkv[a*128 + q4*32]);
    float* satt_w = sqkv + 4096;
    for (int c = 0; c < 128; ++c) {
      float s = dot32r(&wout[c*128 + q4*32], orr);
      s += __shfl_xor(s, 1);
      s += __shfl_xor(s, 2);
      if (q4 == 0) satt_w[a*128 + c] = s + bout[c];
    }
  }
  __syncthreads();

  const float* satt = sqkv + 4096;
  { // attention-weight logits: sum(attended * xm, axis=-1)
    const int a = tid >> 2, q4 = tid & 3;
    float sp = 0.f;
#pragma unroll
    for (int i = 0; i < 32; ++i)
      sp = fmaf(satt[a*128 + q4*32 + i], sx[a*128 + q4*32 + i], sp);
    sp += __shfl_xor(sp, 1);
    sp += __shfl_xor(sp, 2);
    if (q4 == 0) aw_l[a] = sp;
  }
  __syncthreads();

  { // pooling: thread = column c
    float awr[32];
    float mxl = aw_l[0];
#pragma unroll
    for (int a = 1; a < 32; ++a) mxl = fmaxf(mxl, aw_l[a]);
    float se = 0.f;
#pragma unroll
    for (int a = 0; a < 32; ++a) { awr[a] = expf(aw_l[a] - mxl); se += awr[a]; }
    const float inv = 1.f / se;
    const int c = tid;
    float mx = -3.4e38f, sm = 0.f, wm = 0.f, ex = 0.f;
#pragma unroll
    for (int a = 0; a < 32; ++a) {
      const float v = satt[a*128 + c];
      mx = fmaxf(mx, v);
      sm += v;
      wm = fmaf(v, awr[a], wm);
      ex += sx[a*128 + c];
    }
    wm *= inv;
    const float mean = sm * 0.03125f;
    float s2 = 0.f;
#pragma unroll
    for (int a = 0; a < 32; ++a) {
      const float d = satt[a*128 + c] - mean;
      s2 = fmaf(d, d, s2);
    }
    const float stdp = sqrtf(s2 * (1.f/31.f));  // ddof=1
    expl[b*128 + c] = ex * 0.03125f;
    spool[c]       = wm;
    spool[128 + c] = mx;
    spool[256 + c] = mean;
    spool[384 + c] = stdp;
  }
  __syncthreads();

  if (tid < 64) { // proj -> learned[b, k*16+qq]
    const int k = tid >> 4, qq = tid & 15;
    const float* pk = pW + k*2048;
    float s = pb[k*16 + qq];
    for (int h2 = 0; h2 < 128; ++h2)
      s = fmaf(spool[k*128 + h2], pk[h2*16 + qq], s);
    lrn[b*64 + tid] = s;
  }
}

// ---------------- per-(property, molecule) gated MLP heads ----------------
__global__ __launch_bounds__(64) void head_kernel(
    const float* __restrict__ molf, const float* __restrict__ lrn,
    const float* __restrict__ expl,
    const float* __restrict__ mol_gate, const float* __restrict__ lrn_gate,
    const float* __restrict__ meW1, const float* __restrict__ meb1,
    const float* __restrict__ meW2, const float* __restrict__ meb2,
    const float* __restrict__ leW1, const float* __restrict__ leb1,
    const float* __restrict__ leW2, const float* __restrict__ leb2,
    const float* __restrict__ fW1, const float* __restrict__ fb1,
    const float* __restrict__ fW2, const float* __restrict__ fb2,
    const float* __restrict__ hW1, const float* __restrict__ hb1,
    const float* __restrict__ hW2, const float* __restrict__ hb2,
    float* __restrict__ out)
{
  const int b = blockIdx.x, p = blockIdx.y, t = threadIdx.x;
  __shared__ float sgm[200];
  __shared__ float sgl[64];
  __shared__ float sA[64];
  __shared__ float sB[64];
  __shared__ float scomb[256];
  __shared__ float sf1[128];
  __shared__ float sf2[64];

  for (int m = t; m < 200; m += 64)
    sgm[m] = molf[b*200 + m] * sigmoidf_(mol_gate[p*200 + m]);
  sgl[t] = lrn[b*64 + t] * sigmoidf_(lrn_gate[p*64 + t]);
  scomb[t]      = expl[b*128 + t];
  scomb[64 + t] = expl[b*128 + 64 + t];
  __syncthreads();

  {
    float s = meb1[p*64 + t];
    const float* w = meW1 + p*12800;
    for (int m = 0; m < 200; ++m) s = fmaf(sgm[m], w[m*64 + t], s);
    sA[t] = fmaxf(s, 0.f);
    float s2 = leb1[p*64 + t];
    const float* w2 = leW1 + p*4096;
#pragma unroll 8
    for (int m = 0; m < 64; ++m) s2 = fmaf(sgl[m], w2[m*64 + t], s2);
    sB[t] = fmaxf(s2, 0.f);
  }
  __syncthreads();
  {
    float s = meb2[p*64 + t];
    const float* w = meW2 + p*4096;
#pragma unroll 8
    for (int h = 0; h < 64; ++h) s = fmaf(sA[h], w[h*64 + t], s);
    scomb[128 + t] = s;
    float s2 = leb2[p*64 + t];
    const float* w2 = leW2 + p*4096;
#pragma unroll 8
    for (int h = 0; h < 64; ++h) s2 = fmaf(sB[h], w2[h*64 + t], s2);
    scomb[192 + t] = s2;
  }
  __syncthreads();
  {
    const float* w = fW1 + p*32768;
    float s0 = fb1[p*128 + t], s1 = fb1[p*128 + 64 + t];
    for (int c = 0; c < 256; ++c) {
      const float v = scomb[c];
      s0 = fmaf(v, w[c*128 + t], s0);
      s1 = fmaf(v, w[c*128 + 64 + t], s1);
    }
    sf1[t]      = fmaxf(s0, 0.f);
    sf1[64 + t] = fmaxf(s1, 0.f);
  }
  __syncthreads();
  {
    float s = fb2[p*64 + t];
    const float* w = fW2 + p*8192;
    for (int h = 0; h < 128; ++h) s = fmaf(sf1[h], w[h*64 + t], s);
    sf2[t] = s;
  }
  __syncthreads();
  float val = 0.f;
  if (t < 32) {
    float s = hb1[p*32 + t];
    const float* w = hW1 + p*2048;
#pragma unroll 8
    for (int h = 0; h < 64; ++h) s = fmaf(sf2[h], w[h*32 + t], s);
    val = fmaxf(s, 0.f) * hW2[p*32 + t];
  }
#pragma unroll
  for (int o = 1; o < 32; o <<= 1) val += __shfl_xor(val, o);
  if (t == 0) out[p*1024 + b] = val + hb2[p];
}

extern "C" void kernel_launch(void* const* d_in, const int* in_sizes, int n_in,
                              void* d_out, int out_size, void* d_ws, size_t ws_size,
                              hipStream_t stream) {
  const float* x_atoms    = (const float*)d_in[0];
  const float* pos        = (const float*)d_in[1];
  const float* molf       = (const float*)d_in[3];
  const float* emb_W      = (const float*)d_in[4];
  const float* emb_b      = (const float*)d_in[5];
  const float* mp_W1      = (const float*)d_in[6];
  const float* mp_b1      = (const float*)d_in[7];
  const float* mp_W2      = (const float*)d_in[8];
  const float* mp_b2      = (const float*)d_in[9];
  const float* ln_g       = (const float*)d_in[10];
  const float* ln_b       = (const float*)d_in[11];
  const float* attn_in_w  = (const float*)d_in[12];
  const float* attn_in_b  = (const float*)d_in[13];
  const float* attn_out_w = (const float*)d_in[14];
  const float* attn_out_b = (const float*)d_in[15];
  const float* pool_W     = (const float*)d_in[16];
  const float* pool_b     = (const float*)d_in[17];
  const float* mol_gate   = (const float*)d_in[18];
  const float* lrn_gate   = (const float*)d_in[19];
  const float* meW1       = (const float*)d_in[20];
  const float* meb1       = (const float*)d_in[21];
  const float* meW2       = (const float*)d_in[22];
  const float* meb2       = (const float*)d_in[23];
  const float* leW1       = (const float*)d_in[24];
  const float* leb1       = (const float*)d_in[25];
  const float* leW2       = (const float*)d_in[26];
  const float* leb2       = (const float*)d_in[27];
  const float* fW1        = (const float*)d_in[28];
  const float* fb1        = (const float*)d_in[29];
  const float* fW2        = (const float*)d_in[30];
  const float* fb2        = (const float*)d_in[31];
  const float* hW1        = (const float*)d_in[32];
  const float* hb1        = (const float*)d_in[33];
  const float* hW2        = (const float*)d_in[34];
  const float* hb2        = (const float*)d_in[35];
  const int*   ei         = (const int*)d_in[36];

  float* ws   = (float*)d_ws;
  float* x    = ws;                 // N*128
  float* acc  = x + NN*128;         // N*128
  float* df   = acc + NN*128;       // E*3
  float* cntf = df + NE*3;          // N
  float* lrn  = cntf + NN;          // B*64
  float* expl = lrn + 1024*64;      // B*128

  hipMemsetAsync(acc, 0, (size_t)NN*128*sizeof(float), stream);
  hipMemsetAsync(cntf, 0, (size_t)NN*sizeof(float), stream);

  embed_kernel<<<NN, 128, 0, stream>>>(x_atoms, emb_W, emb_b, x);
  dist_cnt_kernel<<<NE/256, 256, 0, stream>>>(pos, ei, df, cntf);
  for (int l = 0; l < 3; ++l) {
    layer_kernel<<<NE/32, 128, 0, stream>>>(x, df, ei,
        mp_W1 + l*259*128, mp_b1 + l*128,
        mp_W2 + l*128*128, mp_b2 + l*128, acc);
    node_update_kernel<<<NN, 64, 0, stream>>>(x, acc, cntf, ln_g + l*128, ln_b + l*128);
  }
  mol_kernel<<<1024, 128, 0, stream>>>(x, attn_in_w, attn_in_b, attn_out_w, attn_out_b,
                                       pool_W, pool_b, expl, lrn);
  head_kernel<<<dim3(1024, 4), 64, 0, stream>>>(molf, lrn, expl, mol_gate, lrn_gate,
      meW1, meb1, meW2, meb2, leW1, leb1, leW2, leb2,
      fW1, fb1, fW2, fb2, hW1, hb1, hW2, hb2, (float*)d_out);
}

// Round 2
// 1475.777 us; speedup vs baseline: 5.5079x; 5.5079x over previous
//
#include <hip/hip_runtime.h>

#define NE 524288
#define NN 32768
#define NB 1024

#define F4(p) (*(const float4*)(p))

__device__ __forceinline__ float sigmoidf_(float v) { return 1.f / (1.f + expf(-v)); }

__device__ __forceinline__ void ld32(float* xr, const float* p) {
#pragma unroll
  for (int i = 0; i < 32; i += 4) {
    float4 v = F4(&p[i]);
    xr[i] = v.x; xr[i+1] = v.y; xr[i+2] = v.z; xr[i+3] = v.w;
  }
}

__device__ __forceinline__ float dot32r(const float* __restrict__ w, const float* xr) {
  float s = 0.f;
#pragma unroll
  for (int i = 0; i < 32; i += 4) {
    float4 ww = F4(&w[i]);
    s = fmaf(xr[i],   ww.x, s);
    s = fmaf(xr[i+1], ww.y, s);
    s = fmaf(xr[i+2], ww.z, s);
    s = fmaf(xr[i+3], ww.w, s);
  }
  return s;
}

// ---------------- embedding: x = x_atoms @ emb_W + emb_b ----------------
__global__ __launch_bounds__(128) void embed_kernel(
    const float* __restrict__ xa, const float* __restrict__ W,
    const float* __restrict__ b, float* __restrict__ x)
{
  __shared__ float a[64];
  const int n = blockIdx.x, t = threadIdx.x;
  if (t < 64) a[t] = xa[n*64 + t];
  __syncthreads();
  float s = b[t];
#pragma unroll 8
  for (int f = 0; f < 64; ++f) s = fmaf(a[f], W[f*128 + t], s);
  x[n*128 + t] = s;
}

// ---------------- CSR build ----------------
__global__ __launch_bounds__(256) void hist_kernel(const int* __restrict__ ei, int* __restrict__ cnt) {
  const int e = blockIdx.x*256 + threadIdx.x;
  atomicAdd(&cnt[ei[NE + e]], 1);
}

__global__ __launch_bounds__(1024) void scan_kernel(
    const int* __restrict__ cnt, int* __restrict__ off, int* __restrict__ cur)
{
  __shared__ int wsum[16];
  const int t = threadIdx.x;
  int local[32];
  const int base = t*32;
  int s = 0;
#pragma unroll
  for (int i = 0; i < 32; ++i) { local[i] = cnt[base+i]; s += local[i]; }
  int pre = s;
  const int lane = t & 63;
#pragma unroll
  for (int o = 1; o < 64; o <<= 1) { int v = __shfl_up(pre, o); if (lane >= o) pre += v; }
  if (lane == 63) wsum[t >> 6] = pre;
  __syncthreads();
  if (t == 0) { int a = 0; for (int w = 0; w < 16; ++w) { int v = wsum[w]; wsum[w] = a; a += v; } }
  __syncthreads();
  int excl = wsum[t >> 6] + pre - s;
#pragma unroll
  for (int i = 0; i < 32; ++i) { off[base+i] = excl; cur[base+i] = excl; excl += local[i]; }
  if (t == 1023) off[NN] = excl;
}

// dist features computed straight into CSR slot order
__global__ __launch_bounds__(256) void scatter_kernel(
    const float* __restrict__ pos, const int* __restrict__ ei,
    int* __restrict__ cur, int* __restrict__ csr_src, float* __restrict__ csr_df)
{
  const int e = blockIdx.x*256 + threadIdx.x;
  const int s = ei[e];
  const int d = ei[NE + e];
  float dx = pos[d*3+0] - pos[s*3+0];
  float dy = pos[d*3+1] - pos[s*3+1];
  float dz = pos[d*3+2] - pos[s*3+2];
  float dist = sqrtf(dx*dx + dy*dy + dz*dz + 1e-12f);
  const int slot = atomicAdd(&cur[d], 1);
  csr_src[slot] = s;
  csr_df[slot*3+0] = dist;
  csr_df[slot*3+1] = 1.f/(1.f + dist);
  csr_df[slot*3+2] = expf(-dist);
}

// ---------------- P = x@W1a + b1 ; Q = x@W1b  (32 nodes/block) ----------------
__global__ __launch_bounds__(128) void pq_kernel(
    const float* __restrict__ x, const float* __restrict__ W1,
    const float* __restrict__ b1, float* __restrict__ P, float* __restrict__ Q)
{
  __shared__ float xT[128*33];
  const int tid = threadIdx.x;
  const int n0 = blockIdx.x * 32;
  for (int idx = tid; idx < 1024; idx += 128) {
    const int n = idx >> 5, c4 = idx & 31;
    float4 v = F4(&x[(n0+n)*128 + c4*4]);
    xT[(c4*4+0)*33 + n] = v.x;
    xT[(c4*4+1)*33 + n] = v.y;
    xT[(c4*4+2)*33 + n] = v.z;
    xT[(c4*4+3)*33 + n] = v.w;
  }
  __syncthreads();

  const int eg = tid & 7, hg = tid >> 3;
  const int e0 = eg*4, h0 = hg*8;
  const float* __restrict__ W1b = W1 + 128*128;

  float pa[4][8], qa[4][8];
#pragma unroll
  for (int j = 0; j < 4; ++j)
#pragma unroll
    for (int i = 0; i < 8; ++i) { pa[j][i] = 0.f; qa[j][i] = 0.f; }

  for (int k = 0; k < 128; ++k) {
    const float4 a4 = F4(&xT[k*33 + e0]);
    const float4 p0 = F4(&W1[k*128 + h0]);
    const float4 p1 = F4(&W1[k*128 + h0 + 4]);
    const float4 q0 = F4(&W1b[k*128 + h0]);
    const float4 q1 = F4(&W1b[k*128 + h0 + 4]);
    const float av[4] = {a4.x, a4.y, a4.z, a4.w};
    const float pv[8] = {p0.x, p0.y, p0.z, p0.w, p1.x, p1.y, p1.z, p1.w};
    const float qv[8] = {q0.x, q0.y, q0.z, q0.w, q1.x, q1.y, q1.z, q1.w};
#pragma unroll
    for (int j = 0; j < 4; ++j)
#pragma unroll
      for (int i = 0; i < 8; ++i) {
        pa[j][i] = fmaf(av[j], pv[i], pa[j][i]);
        qa[j][i] = fmaf(av[j], qv[i], qa[j][i]);
      }
  }

  const float4 blo = F4(&b1[h0]);
  const float4 bhi = F4(&b1[h0+4]);
#pragma unroll
  for (int j = 0; j < 4; ++j) {
    const int row = (n0 + e0 + j)*128 + h0;
    *(float4*)&P[row]   = make_float4(pa[j][0]+blo.x, pa[j][1]+blo.y, pa[j][2]+blo.z, pa[j][3]+blo.w);
    *(float4*)&P[row+4] = make_float4(pa[j][4]+bhi.x, pa[j][5]+bhi.y, pa[j][6]+bhi.z, pa[j][7]+bhi.w);
    *(float4*)&Q[row]   = make_float4(qa[j][0], qa[j][1], qa[j][2], qa[j][3]);
    *(float4*)&Q[row+4] = make_float4(qa[j][4], qa[j][5], qa[j][6], qa[j][7]);
  }
}

// ---------------- node-centric aggregation: P[n] <- mean_e relu(P[n]+Q[src]+df@W1c) ----------------
__global__ __launch_bounds__(256) void agg_kernel(
    float* __restrict__ P, const float* __restrict__ Q,
    const int* __restrict__ csr_off, const int* __restrict__ csr_src,
    const float* __restrict__ csr_df, const float* __restrict__ W1)
{
  const int tid = threadIdx.x;
  const int node = blockIdx.x*4 + (tid >> 6);
  const int lane = tid & 63;
  const int c0 = lane*2;
  const int off0 = csr_off[node], off1 = csr_off[node+1];

  const float* __restrict__ w1c = W1 + 256*128;
  const float w00 = w1c[c0],       w01 = w1c[c0+1];
  const float w10 = w1c[128+c0],   w11 = w1c[128+c0+1];
  const float w20 = w1c[256+c0],   w21 = w1c[256+c0+1];
  const float2 p = *(const float2*)&P[node*128 + c0];

  float a0 = 0.f, a1 = 0.f;
  for (int base = off0; base < off1; base += 64) {
    const int m = min(64, off1 - base);
    int msrc = 0; float md0 = 0.f, md1 = 0.f, md2 = 0.f;
    if (lane < m) {
      msrc = csr_src[base + lane];
      const float* dp = &csr_df[(base + lane)*3];
      md0 = dp[0]; md1 = dp[1]; md2 = dp[2];
    }
#pragma unroll 4
    for (int j = 0; j < m; ++j) {
      const int src = __shfl(msrc, j);
      const float d0 = __shfl(md0, j), d1 = __shfl(md1, j), d2 = __shfl(md2, j);
      const float2 q = *(const float2*)&Q[src*128 + c0];
      float h0 = p.x + q.x;
      h0 = fmaf(d0, w00, h0); h0 = fmaf(d1, w10, h0); h0 = fmaf(d2, w20, h0);
      float h1 = p.y + q.y;
      h1 = fmaf(d0, w01, h1); h1 = fmaf(d1, w11, h1); h1 = fmaf(d2, w21, h1);
      a0 += fmaxf(h0, 0.f);
      a1 += fmaxf(h1, 0.f);
    }
  }
  const int deg = off1 - off0;
  const float rc = deg > 0 ? 1.f/(float)deg : 1.f;
  *(float2*)&P[node*128 + c0] = make_float2(a0*rc, a1*rc);
}

// ---------------- x <- LN(P@W2 + (deg>0)*b2 + x) ----------------
__global__ __launch_bounds__(128) void gemm_ln_kernel(
    const float* __restrict__ A /*agg, in P*/, const float* __restrict__ W2,
    const float* __restrict__ b2, const int* __restrict__ csr_off,
    const float* __restrict__ g, const float* __restrict__ bb,
    float* __restrict__ x)
{
  __shared__ float smem[128*33];  // xT staging, then reused as out tile [32][132]
  const int tid = threadIdx.x;
  const int n0 = blockIdx.x * 32;
  for (int idx = tid; idx < 1024; idx += 128) {
    const int n = idx >> 5, c4 = idx & 31;
    float4 v = F4(&A[(n0+n)*128 + c4*4]);
    smem[(c4*4+0)*33 + n] = v.x;
    smem[(c4*4+1)*33 + n] = v.y;
    smem[(c4*4+2)*33 + n] = v.z;
    smem[(c4*4+3)*33 + n] = v.w;
  }
  __syncthreads();

  const int eg = tid & 7, hg = tid >> 3;
  const int e0 = eg*4, h0 = hg*8;

  float acc[4][8];
#pragma unroll
  for (int j = 0; j < 4; ++j)
#pragma unroll
    for (int i = 0; i < 8; ++i) acc[j][i] = 0.f;

  for (int k = 0; k < 128; ++k) {
    const float4 a4 = F4(&smem[k*33 + e0]);
    const float4 w0 = F4(&W2[k*128 + h0]);
    const float4 w1 = F4(&W2[k*128 + h0 + 4]);
    const float av[4] = {a4.x, a4.y, a4.z, a4.w};
    const float wv[8] = {w0.x, w0.y, w0.z, w0.w, w1.x, w1.y, w1.z, w1.w};
#pragma unroll
    for (int j = 0; j < 4; ++j)
#pragma unroll
      for (int i = 0; i < 8; ++i)
        acc[j][i] = fmaf(av[j], wv[i], acc[j][i]);
  }
  __syncthreads();  // done reading staged A

  const float4 blo = F4(&b2[h0]);
  const float4 bhi = F4(&b2[h0+4]);
#pragma unroll
  for (int j = 0; j < 4; ++j) {
    const int n = n0 + e0 + j;
    const float s = (csr_off[n+1] > csr_off[n]) ? 1.f : 0.f;
    const float4 x0 = F4(&x[n*128 + h0]);
    const float4 x1 = F4(&x[n*128 + h0 + 4]);
    float* o = &smem[(e0+j)*132 + h0];
    o[0] = acc[j][0] + s*blo.x + x0.x;
    o[1] = acc[j][1] + s*blo.y + x0.y;
    o[2] = acc[j][2] + s*blo.z + x0.z;
    o[3] = acc[j][3] + s*blo.w + x0.w;
    o[4] = acc[j][4] + s*bhi.x + x1.x;
    o[5] = acc[j][5] + s*bhi.y + x1.y;
    o[6] = acc[j][6] + s*bhi.z + x1.z;
    o[7] = acc[j][7] + s*bhi.w + x1.w;
  }
  __syncthreads();

  // layernorm: 4 threads per row
  const int a = tid >> 2, q4 = tid & 3;
  const float* row = &smem[a*132 + q4*32];
  float s1 = 0.f, s2 = 0.f;
#pragma unroll
  for (int i = 0; i < 32; ++i) { const float v = row[i]; s1 += v; s2 = fmaf(v, v, s2); }
  s1 += __shfl_xor(s1, 1); s2 += __shfl_xor(s2, 1);
  s1 += __shfl_xor(s1, 2); s2 += __shfl_xor(s2, 2);
  const float mu = s1 * (1.f/128.f);
  const float var = s2 * (1.f/128.f) - mu*mu;
  const float rstd = rsqrtf(var + 1e-5f);
#pragma unroll
  for (int i = 0; i < 32; i += 4) {
    const float4 gg = F4(&g[q4*32 + i]);
    const float4 bv = F4(&bb[q4*32 + i]);
    float4 o;
    o.x = (row[i]   - mu)*rstd*gg.x + bv.x;
    o.y = (row[i+1] - mu)*rstd*gg.y + bv.y;
    o.z = (row[i+2] - mu)*rstd*gg.z + bv.z;
    o.w = (row[i+3] - mu)*rstd*gg.w + bv.w;
    *(float4*)&x[(n0+a)*128 + q4*32 + i] = o;
  }
}

// ---------------- per-molecule MHA + pooling + proj ----------------
__global__ __launch_bounds__(128) void mol_kernel(
    const float* __restrict__ x,
    const float* __restrict__ win, const float* __restrict__ bin,
    const float* __restrict__ wout, const float* __restrict__ bout,
    const float* __restrict__ pW, const float* __restrict__ pb,
    float* __restrict__ expl, float* __restrict__ lrn)
{
  __shared__ float sx[4096];
  __shared__ float sqkv[12288];
  __shared__ float aw_l[32];
  __shared__ float spool[512];
  const int tid = threadIdx.x;
  const int b = blockIdx.x;

  for (int i = tid; i < 4096; i += 128) sx[i] = x[b*4096 + i];
  __syncthreads();

  { // qkv = xm @ win.T + bin
    const int a = tid >> 2, q4 = tid & 3;
    float xr[32];
    ld32(xr, &sx[a*128 + q4*32]);
    for (int c = 0; c < 384; ++c) {
      float s = dot32r(&win[c*128 + q4*32], xr);
      s += __shfl_xor(s, 1);
      s += __shfl_xor(s, 2);
      if (q4 == 0) sqkv[(c >> 7)*4096 + a*128 + (c & 127)] = s + bin[c];
    }
  }
  __syncthreads();

  { // per-head attention
    const int h = tid >> 5, qr = tid & 31;
    const float* sq = sqkv;
    const float* sk = sqkv + 4096;
    const float* sv = sqkv + 8192;
    float qreg[32];
    ld32(qreg, &sq[qr*128 + h*32]);
    float sc[32];
#pragma unroll
    for (int k = 0; k < 32; ++k)
      sc[k] = dot32r(&sk[k*128 + h*32], qreg) * 0.17677669529663687f;
    float mx = sc[0];
#pragma unroll
    for (int k = 1; k < 32; ++k) mx = fmaxf(mx, sc[k]);
    float se = 0.f;
#pragma unroll
    for (int k = 0; k < 32; ++k) { sc[k] = expf(sc[k] - mx); se += sc[k]; }
    const float inv = 1.f / se;
    float od[32];
#pragma unroll
    for (int i = 0; i < 32; ++i) od[i] = 0.f;
#pragma unroll
    for (int k = 0; k < 32; ++k) {
      const float w = sc[k] * inv;
      const float* vr = &sv[k*128 + h*32];
#pragma unroll
      for (int i = 0; i < 32; i += 4) {
        float4 v = F4(&vr[i]);
        od[i]   = fmaf(w, v.x, od[i]);
        od[i+1] = fmaf(w, v.y, od[i+1]);
        od[i+2] = fmaf(w, v.z, od[i+2]);
        od[i+3] = fmaf(w, v.w, od[i+3]);
      }
    }
    __syncthreads();
#pragma unroll
    for (int i = 0; i < 32; i += 4)
      *(float4*)&sqkv[qr*128 + h*32 + i] = make_float4(od[i], od[i+1], od[i+2], od[i+3]);
  }
  __syncthreads();

  { // attended = o @ wout.T + bout
    const int a = tid >> 2, q4 = tid & 3;
    float orr[32];
    ld32(orr, &sqkv[a*128 + q4*32]);
    float* satt_w = sqkv + 4096;
    for (int c = 0; c < 128; ++c) {
      float s = dot32r(&wout[c*128 + q4*32], orr);
      s += __shfl_xor(s, 1);
      s += __shfl_xor(s, 2);
      if (q4 == 0) satt_w[a*128 + c] = s + bout[c];
    }
  }
  __syncthreads();

  const float* satt = sqkv + 4096;
  {
    const int a = tid >> 2, q4 = tid & 3;
    float sp = 0.f;
#pragma unroll
    for (int i = 0; i < 32; ++i)
      sp = fmaf(satt[a*128 + q4*32 + i], sx[a*128 + q4*32 + i], sp);
    sp += __shfl_xor(sp, 1);
    sp += __shfl_xor(sp, 2);
    if (q4 == 0) aw_l[a] = sp;
  }
  __syncthreads();

  { // pooling per column
    float awr[32];
    float mxl = aw_l[0];
#pragma unroll
    for (int a = 1; a < 32; ++a) mxl = fmaxf(mxl, aw_l[a]);
    float se = 0.f;
#pragma unroll
    for (int a = 0; a < 32; ++a) { awr[a] = expf(aw_l[a] - mxl); se += awr[a]; }
    const float inv = 1.f / se;
    const int c = tid;
    float mx = -3.4e38f, sm = 0.f, wm = 0.f, ex = 0.f;
#pragma unroll
    for (int a = 0; a < 32; ++a) {
      const float v = satt[a*128 + c];
      mx = fmaxf(mx, v);
      sm += v;
      wm = fmaf(v, awr[a], wm);
      ex += sx[a*128 + c];
    }
    wm *= inv;
    const float mean = sm * 0.03125f;
    float s2 = 0.f;
#pragma unroll
    for (int a = 0; a < 32; ++a) {
      const float d = satt[a*128 + c] - mean;
      s2 = fmaf(d, d, s2);
    }
    const float stdp = sqrtf(s2 * (1.f/31.f));
    expl[b*128 + c] = ex * 0.03125f;
    spool[c]       = wm;
    spool[128 + c] = mx;
    spool[256 + c] = mean;
    spool[384 + c] = stdp;
  }
  __syncthreads();

  if (tid < 64) {
    const int k = tid >> 4, qq = tid & 15;
    const float* pk = pW + k*2048;
    float s = pb[k*16 + qq];
    for (int h2 = 0; h2 < 128; ++h2)
      s = fmaf(spool[k*128 + h2], pk[h2*16 + qq], s);
    lrn[b*64 + tid] = s;
  }
}

// ---------------- per-(property, molecule) gated MLP heads ----------------
__global__ __launch_bounds__(64) void head_kernel(
    const float* __restrict__ molf, const float* __restrict__ lrn,
    const float* __restrict__ expl,
    const float* __restrict__ mol_gate, const float* __restrict__ lrn_gate,
    const float* __restrict__ meW1, const float* __restrict__ meb1,
    const float* __restrict__ meW2, const float* __restrict__ meb2,
    const float* __restrict__ leW1, const float* __restrict__ leb1,
    const float* __restrict__ leW2, const float* __restrict__ leb2,
    const float* __restrict__ fW1, const float* __restrict__ fb1,
    const float* __restrict__ fW2, const float* __restrict__ fb2,
    const float* __restrict__ hW1, const float* __restrict__ hb1,
    const float* __restrict__ hW2, const float* __restrict__ hb2,
    float* __restrict__ out)
{
  const int b = blockIdx.x, p = blockIdx.y, t = threadIdx.x;
  __shared__ float sgm[200];
  __shared__ float sgl[64];
  __shared__ float sA[64];
  __shared__ float sB[64];
  __shared__ float scomb[256];
  __shared__ float sf1[128];
  __shared__ float sf2[64];

  for (int m = t; m < 200; m += 64)
    sgm[m] = molf[b*200 + m] * sigmoidf_(mol_gate[p*200 + m]);
  sgl[t] = lrn[b*64 + t] * sigmoidf_(lrn_gate[p*64 + t]);
  scomb[t]      = expl[b*128 + t];
  scomb[64 + t] = expl[b*128 + 64 + t];
  __syncthreads();

  {
    float s = meb1[p*64 + t];
    const float* w = meW1 + p*12800;
    for (int m = 0; m < 200; ++m) s = fmaf(sgm[m], w[m*64 + t], s);
    sA[t] = fmaxf(s, 0.f);
    float s2 = leb1[p*64 + t];
    const float* w2 = leW1 + p*4096;
#pragma unroll 8
    for (int m = 0; m < 64; ++m) s2 = fmaf(sgl[m], w2[m*64 + t], s2);
    sB[t] = fmaxf(s2, 0.f);
  }
  __syncthreads();
  {
    float s = meb2[p*64 + t];
    const float* w = meW2 + p*4096;
#pragma unroll 8
    for (int h = 0; h < 64; ++h) s = fmaf(sA[h], w[h*64 + t], s);
    scomb[128 + t] = s;
    float s2 = leb2[p*64 + t];
    const float* w2 = leW2 + p*4096;
#pragma unroll 8
    for (int h = 0; h < 64; ++h) s2 = fmaf(sB[h], w2[h*64 + t], s2);
    scomb[192 + t] = s2;
  }
  __syncthreads();
  {
    const float* w = fW1 + p*32768;
    float s0 = fb1[p*128 + t], s1 = fb1[p*128 + 64 + t];
    for (int c = 0; c < 256; ++c) {
      const float v = scomb[c];
      s0 = fmaf(v, w[c*128 + t], s0);
      s1 = fmaf(v, w[c*128 + 64 + t], s1);
    }
    sf1[t]      = fmaxf(s0, 0.f);
    sf1[64 + t] = fmaxf(s1, 0.f);
  }
  __syncthreads();
  {
    float s = fb2[p*64 + t];
    const float* w = fW2 + p*8192;
    for (int h = 0; h < 128; ++h) s = fmaf(sf1[h], w[h*64 + t], s);
    sf2[t] = s;
  }
  __syncthreads();
  float val = 0.f;
  if (t < 32) {
    float s = hb1[p*32 + t];
    const float* w = hW1 + p*2048;
#pragma unroll 8
    for (int h = 0; h < 64; ++h) s = fmaf(sf2[h], w[h*32 + t], s);
    val = fmaxf(s, 0.f) * hW2[p*32 + t];
  }
#pragma unroll
  for (int o = 1; o < 32; o <<= 1) val += __shfl_xor(val, o);
  if (t == 0) out[p*1024 + b] = val + hb2[p];
}

extern "C" void kernel_launch(void* const* d_in, const int* in_sizes, int n_in,
                              void* d_out, int out_size, void* d_ws, size_t ws_size,
                              hipStream_t stream) {
  const float* x_atoms    = (const float*)d_in[0];
  const float* pos        = (const float*)d_in[1];
  const float* molf       = (const float*)d_in[3];
  const float* emb_W      = (const float*)d_in[4];
  const float* emb_b      = (const float*)d_in[5];
  const float* mp_W1      = (const float*)d_in[6];
  const float* mp_b1      = (const float*)d_in[7];
  const float* mp_W2      = (const float*)d_in[8];
  const float* mp_b2      = (const float*)d_in[9];
  const float* ln_g       = (const float*)d_in[10];
  const float* ln_b       = (const float*)d_in[11];
  const float* attn_in_w  = (const float*)d_in[12];
  const float* attn_in_b  = (const float*)d_in[13];
  const float* attn_out_w = (const float*)d_in[14];
  const float* attn_out_b = (const float*)d_in[15];
  const float* pool_W     = (const float*)d_in[16];
  const float* pool_b     = (const float*)d_in[17];
  const float* mol_gate   = (const float*)d_in[18];
  const float* lrn_gate   = (const float*)d_in[19];
  const float* meW1       = (const float*)d_in[20];
  const float* meb1       = (const float*)d_in[21];
  const float* meW2       = (const float*)d_in[22];
  const float* meb2       = (const float*)d_in[23];
  const float* leW1       = (const float*)d_in[24];
  const float* leb1       = (const float*)d_in[25];
  const float* leW2       = (const float*)d_in[26];
  const float* leb2       = (const float*)d_in[27];
  const float* fW1        = (const float*)d_in[28];
  const float* fb1        = (const float*)d_in[29];
  const float* fW2        = (const float*)d_in[30];
  const float* fb2        = (const float*)d_in[31];
  const float* hW1        = (const float*)d_in[32];
  const float* hb1        = (const float*)d_in[33];
  const float* hW2        = (const float*)d_in[34];
  const float* hb2        = (const float*)d_in[35];
  const int*   ei         = (const int*)d_in[36];

  float* ws      = (float*)d_ws;
  float* x       = ws;                       // NN*128
  float* P       = x + (size_t)NN*128;       // NN*128
  float* Q       = P + (size_t)NN*128;       // NN*128
  float* csr_df  = Q + (size_t)NN*128;       // NE*3
  int*   csr_src = (int*)(csr_df + (size_t)NE*3); // NE
  int*   cnt_i   = csr_src + NE;             // NN
  int*   csr_off = cnt_i + NN;               // NN+1
  int*   cur     = csr_off + NN + 1;         // NN
  float* lrn     = (float*)(cur + NN);       // NB*64
  float* expl    = lrn + NB*64;              // NB*128

  hipMemsetAsync(cnt_i, 0, (size_t)NN*sizeof(int), stream);

  embed_kernel<<<NN, 128, 0, stream>>>(x_atoms, emb_W, emb_b, x);
  hist_kernel<<<NE/256, 256, 0, stream>>>(ei, cnt_i);
  scan_kernel<<<1, 1024, 0, stream>>>(cnt_i, csr_off, cur);
  scatter_kernel<<<NE/256, 256, 0, stream>>>(pos, ei, cur, csr_src, csr_df);

  for (int l = 0; l < 3; ++l) {
    const float* W1l = mp_W1 + (size_t)l*259*128;
    pq_kernel<<<NN/32, 128, 0, stream>>>(x, W1l, mp_b1 + l*128, P, Q);
    agg_kernel<<<NN/4, 256, 0, stream>>>(P, Q, csr_off, csr_src, csr_df, W1l);
    gemm_ln_kernel<<<NN/32, 128, 0, stream>>>(P, mp_W2 + (size_t)l*128*128, mp_b2 + l*128,
                                              csr_off, ln_g + l*128, ln_b + l*128, x);
  }

  mol_kernel<<<NB, 128, 0, stream>>>(x, attn_in_w, attn_in_b, attn_out_w, attn_out_b,
                                     pool_W, pool_b, expl, lrn);
  head_kernel<<<dim3(NB, 4), 64, 0, stream>>>(molf, lrn, expl, mol_gate, lrn_gate,
      meW1, meb1, meW2, meb2, leW1, leb1, leW2, leb2,
      fW1, fb1, fW2, fb2, hW1, hb1, hW2, hb2, (float*)d_out);
}

// Round 3
// 679.904 us; speedup vs baseline: 11.9554x; 2.1706x over previous
//
#include <hip/hip_runtime.h>

#define NE 524288
#define NN 32768
#define NB 1024

#define F4(p) (*(const float4*)(p))

__device__ __forceinline__ float sigmoidf_(float v) { return 1.f / (1.f + expf(-v)); }

__device__ __forceinline__ void ld32(float* xr, const float* p) {
#pragma unroll
  for (int i = 0; i < 32; i += 4) {
    float4 v = F4(&p[i]);
    xr[i] = v.x; xr[i+1] = v.y; xr[i+2] = v.z; xr[i+3] = v.w;
  }
}

__device__ __forceinline__ float dot32r(const float* __restrict__ w, const float* xr) {
  float s = 0.f;
#pragma unroll
  for (int i = 0; i < 32; i += 4) {
    float4 ww = F4(&w[i]);
    s = fmaf(xr[i],   ww.x, s);
    s = fmaf(xr[i+1], ww.y, s);
    s = fmaf(xr[i+2], ww.z, s);
    s = fmaf(xr[i+3], ww.w, s);
  }
  return s;
}

// ---------------- embedding ----------------
__global__ __launch_bounds__(128) void embed_kernel(
    const float* __restrict__ xa, const float* __restrict__ W,
    const float* __restrict__ b, float* __restrict__ x)
{
  __shared__ float a[64];
  const int n = blockIdx.x, t = threadIdx.x;
  if (t < 64) a[t] = xa[n*64 + t];
  __syncthreads();
  float s = b[t];
#pragma unroll 8
  for (int f = 0; f < 64; ++f) s = fmaf(a[f], W[f*128 + t], s);
  x[n*128 + t] = s;
}

// ---------------- CSR build ----------------
__global__ __launch_bounds__(256) void hist_kernel(const int* __restrict__ ei, int* __restrict__ cnt) {
  const int e = blockIdx.x*256 + threadIdx.x;
  atomicAdd(&cnt[ei[NE + e]], 1);
}

__global__ __launch_bounds__(1024) void scan_kernel(
    const int* __restrict__ cnt, int* __restrict__ off, int* __restrict__ cur)
{
  __shared__ int wsum[16];
  const int t = threadIdx.x;
  int local[32];
  const int base = t*32;
  int s = 0;
#pragma unroll
  for (int i = 0; i < 32; ++i) { local[i] = cnt[base+i]; s += local[i]; }
  int pre = s;
  const int lane = t & 63;
#pragma unroll
  for (int o = 1; o < 64; o <<= 1) { int v = __shfl_up(pre, o); if (lane >= o) pre += v; }
  if (lane == 63) wsum[t >> 6] = pre;
  __syncthreads();
  if (t == 0) { int a = 0; for (int w = 0; w < 16; ++w) { int v = wsum[w]; wsum[w] = a; a += v; } }
  __syncthreads();
  int excl = wsum[t >> 6] + pre - s;
#pragma unroll
  for (int i = 0; i < 32; ++i) { off[base+i] = excl; cur[base+i] = excl; excl += local[i]; }
  if (t == 1023) off[NN] = excl;
}

__global__ __launch_bounds__(256) void scatter_kernel(
    const float* __restrict__ pos, const int* __restrict__ ei,
    int* __restrict__ cur, int* __restrict__ csr_src, float* __restrict__ csr_df)
{
  const int e = blockIdx.x*256 + threadIdx.x;
  const int s = ei[e];
  const int d = ei[NE + e];
  float dx = pos[d*3+0] - pos[s*3+0];
  float dy = pos[d*3+1] - pos[s*3+1];
  float dz = pos[d*3+2] - pos[s*3+2];
  float dist = sqrtf(dx*dx + dy*dy + dz*dz + 1e-12f);
  const int slot = atomicAdd(&cur[d], 1);
  csr_src[slot] = s;
  csr_df[slot*3+0] = dist;
  csr_df[slot*3+1] = 1.f/(1.f + dist);
  csr_df[slot*3+2] = expf(-dist);
}

// ---------------- 32x32 tile transpose: out[c][r] = in[r][c] ----------------
__global__ __launch_bounds__(256) void transpose_kernel(
    const float* __restrict__ in, float* __restrict__ out, int rows, int cols)
{
  __shared__ float tile[32][33];
  const int c0 = blockIdx.x*32, r0 = blockIdx.y*32;
  const int t = threadIdx.x;
  const int tr = t >> 5, tc = t & 31;
  for (int i = tr; i < 32; i += 8)
    tile[i][tc] = in[(r0+i)*cols + (c0+tc)];
  __syncthreads();
  for (int i = tr; i < 32; i += 8)
    out[(c0+i)*rows + (r0+tc)] = tile[tc][i];
}

// ---------------- P = x@W1a + b1 ; Q = x@W1b ----------------
__global__ __launch_bounds__(128) void pq_kernel(
    const float* __restrict__ x, const float* __restrict__ W1,
    const float* __restrict__ b1, float* __restrict__ P, float* __restrict__ Q)
{
  __shared__ float xT[128*33];
  const int tid = threadIdx.x;
  const int n0 = blockIdx.x * 32;
  for (int idx = tid; idx < 1024; idx += 128) {
    const int n = idx >> 5, c4 = idx & 31;
    float4 v = F4(&x[(n0+n)*128 + c4*4]);
    xT[(c4*4+0)*33 + n] = v.x;
    xT[(c4*4+1)*33 + n] = v.y;
    xT[(c4*4+2)*33 + n] = v.z;
    xT[(c4*4+3)*33 + n] = v.w;
  }
  __syncthreads();

  const int eg = tid & 7, hg = tid >> 3;
  const int e0 = eg*4, h0 = hg*8;
  const float* __restrict__ W1b = W1 + 128*128;

  float pa[4][8], qa[4][8];
#pragma unroll
  for (int j = 0; j < 4; ++j)
#pragma unroll
    for (int i = 0; i < 8; ++i) { pa[j][i] = 0.f; qa[j][i] = 0.f; }

  for (int k = 0; k < 128; ++k) {
    const float4 a4 = F4(&xT[k*33 + e0]);
    const float4 p0 = F4(&W1[k*128 + h0]);
    const float4 p1 = F4(&W1[k*128 + h0 + 4]);
    const float4 q0 = F4(&W1b[k*128 + h0]);
    const float4 q1 = F4(&W1b[k*128 + h0 + 4]);
    const float av[4] = {a4.x, a4.y, a4.z, a4.w};
    const float pv[8] = {p0.x, p0.y, p0.z, p0.w, p1.x, p1.y, p1.z, p1.w};
    const float qv[8] = {q0.x, q0.y, q0.z, q0.w, q1.x, q1.y, q1.z, q1.w};
#pragma unroll
    for (int j = 0; j < 4; ++j)
#pragma unroll
      for (int i = 0; i < 8; ++i) {
        pa[j][i] = fmaf(av[j], pv[i], pa[j][i]);
        qa[j][i] = fmaf(av[j], qv[i], qa[j][i]);
      }
  }

  const float4 blo = F4(&b1[h0]);
  const float4 bhi = F4(&b1[h0+4]);
#pragma unroll
  for (int j = 0; j < 4; ++j) {
    const int row = (n0 + e0 + j)*128 + h0;
    *(float4*)&P[row]   = make_float4(pa[j][0]+blo.x, pa[j][1]+blo.y, pa[j][2]+blo.z, pa[j][3]+blo.w);
    *(float4*)&P[row+4] = make_float4(pa[j][4]+bhi.x, pa[j][5]+bhi.y, pa[j][6]+bhi.z, pa[j][7]+bhi.w);
    *(float4*)&Q[row]   = make_float4(qa[j][0], qa[j][1], qa[j][2], qa[j][3]);
    *(float4*)&Q[row+4] = make_float4(qa[j][4], qa[j][5], qa[j][6], qa[j][7]);
  }
}

// ---------------- aggregation ----------------
__global__ __launch_bounds__(256) void agg_kernel(
    float* __restrict__ P, const float* __restrict__ Q,
    const int* __restrict__ csr_off, const int* __restrict__ csr_src,
    const float* __restrict__ csr_df, const float* __restrict__ W1)
{
  const int tid = threadIdx.x;
  const int node = blockIdx.x*4 + (tid >> 6);
  const int lane = tid & 63;
  const int c0 = lane*2;
  const int off0 = csr_off[node], off1 = csr_off[node+1];

  const float* __restrict__ w1c = W1 + 256*128;
  const float w00 = w1c[c0],       w01 = w1c[c0+1];
  const float w10 = w1c[128+c0],   w11 = w1c[128+c0+1];
  const float w20 = w1c[256+c0],   w21 = w1c[256+c0+1];
  const float2 p = *(const float2*)&P[node*128 + c0];

  float a0 = 0.f, a1 = 0.f;
  for (int base = off0; base < off1; base += 64) {
    const int m = min(64, off1 - base);
    int msrc = 0; float md0 = 0.f, md1 = 0.f, md2 = 0.f;
    if (lane < m) {
      msrc = csr_src[base + lane];
      const float* dp = &csr_df[(base + lane)*3];
      md0 = dp[0]; md1 = dp[1]; md2 = dp[2];
    }
#pragma unroll 4
    for (int j = 0; j < m; ++j) {
      const int src = __shfl(msrc, j);
      const float d0 = __shfl(md0, j), d1 = __shfl(md1, j), d2 = __shfl(md2, j);
      const float2 q = *(const float2*)&Q[src*128 + c0];
      float h0 = p.x + q.x;
      h0 = fmaf(d0, w00, h0); h0 = fmaf(d1, w10, h0); h0 = fmaf(d2, w20, h0);
      float h1 = p.y + q.y;
      h1 = fmaf(d0, w01, h1); h1 = fmaf(d1, w11, h1); h1 = fmaf(d2, w21, h1);
      a0 += fmaxf(h0, 0.f);
      a1 += fmaxf(h1, 0.f);
    }
  }
  const int deg = off1 - off0;
  const float rc = deg > 0 ? 1.f/(float)deg : 1.f;
  *(float2*)&P[node*128 + c0] = make_float2(a0*rc, a1*rc);
}

// ---------------- x <- LN(P@W2 + (deg>0)*b2 + x) ----------------
__global__ __launch_bounds__(128) void gemm_ln_kernel(
    const float* __restrict__ A, const float* __restrict__ W2,
    const float* __restrict__ b2, const int* __restrict__ csr_off,
    const float* __restrict__ g, const float* __restrict__ bb,
    float* __restrict__ x)
{
  __shared__ float smem[128*33];
  const int tid = threadIdx.x;
  const int n0 = blockIdx.x * 32;
  for (int idx = tid; idx < 1024; idx += 128) {
    const int n = idx >> 5, c4 = idx & 31;
    float4 v = F4(&A[(n0+n)*128 + c4*4]);
    smem[(c4*4+0)*33 + n] = v.x;
    smem[(c4*4+1)*33 + n] = v.y;
    smem[(c4*4+2)*33 + n] = v.z;
    smem[(c4*4+3)*33 + n] = v.w;
  }
  __syncthreads();

  const int eg = tid & 7, hg = tid >> 3;
  const int e0 = eg*4, h0 = hg*8;

  float acc[4][8];
#pragma unroll
  for (int j = 0; j < 4; ++j)
#pragma unroll
    for (int i = 0; i < 8; ++i) acc[j][i] = 0.f;

  for (int k = 0; k < 128; ++k) {
    const float4 a4 = F4(&smem[k*33 + e0]);
    const float4 w0 = F4(&W2[k*128 + h0]);
    const float4 w1 = F4(&W2[k*128 + h0 + 4]);
    const float av[4] = {a4.x, a4.y, a4.z, a4.w};
    const float wv[8] = {w0.x, w0.y, w0.z, w0.w, w1.x, w1.y, w1.z, w1.w};
#pragma unroll
    for (int j = 0; j < 4; ++j)
#pragma unroll
      for (int i = 0; i < 8; ++i)
        acc[j][i] = fmaf(av[j], wv[i], acc[j][i]);
  }
  __syncthreads();

  const float4 blo = F4(&b2[h0]);
  const float4 bhi = F4(&b2[h0+4]);
#pragma unroll
  for (int j = 0; j < 4; ++j) {
    const int n = n0 + e0 + j;
    const float s = (csr_off[n+1] > csr_off[n]) ? 1.f : 0.f;
    const float4 x0 = F4(&x[n*128 + h0]);
    const float4 x1 = F4(&x[n*128 + h0 + 4]);
    float* o = &smem[(e0+j)*132 + h0];
    o[0] = acc[j][0] + s*blo.x + x0.x;
    o[1] = acc[j][1] + s*blo.y + x0.y;
    o[2] = acc[j][2] + s*blo.z + x0.z;
    o[3] = acc[j][3] + s*blo.w + x0.w;
    o[4] = acc[j][4] + s*bhi.x + x1.x;
    o[5] = acc[j][5] + s*bhi.y + x1.y;
    o[6] = acc[j][6] + s*bhi.z + x1.z;
    o[7] = acc[j][7] + s*bhi.w + x1.w;
  }
  __syncthreads();

  const int a = tid >> 2, q4 = tid & 3;
  const float* row = &smem[a*132 + q4*32];
  float s1 = 0.f, s2 = 0.f;
#pragma unroll
  for (int i = 0; i < 32; ++i) { const float v = row[i]; s1 += v; s2 = fmaf(v, v, s2); }
  s1 += __shfl_xor(s1, 1); s2 += __shfl_xor(s2, 1);
  s1 += __shfl_xor(s1, 2); s2 += __shfl_xor(s2, 2);
  const float mu = s1 * (1.f/128.f);
  const float var = s2 * (1.f/128.f) - mu*mu;
  const float rstd = rsqrtf(var + 1e-5f);
#pragma unroll
  for (int i = 0; i < 32; i += 4) {
    const float4 gg = F4(&g[q4*32 + i]);
    const float4 bv = F4(&bb[q4*32 + i]);
    float4 o;
    o.x = (row[i]   - mu)*rstd*gg.x + bv.x;
    o.y = (row[i+1] - mu)*rstd*gg.y + bv.y;
    o.z = (row[i+2] - mu)*rstd*gg.z + bv.z;
    o.w = (row[i+3] - mu)*rstd*gg.w + bv.w;
    *(float4*)&x[(n0+a)*128 + q4*32 + i] = o;
  }
}

// ---------------- qkv = x @ winT + bin -> dq,dk,dv [N,128] each ----------------
__global__ __launch_bounds__(128) void qkv_kernel(
    const float* __restrict__ x, const float* __restrict__ winT,
    const float* __restrict__ bin,
    float* __restrict__ dq, float* __restrict__ dk, float* __restrict__ dv)
{
  __shared__ float xT[128*33];
  const int tid = threadIdx.x;
  const int n0 = blockIdx.x * 32;
  for (int idx = tid; idx < 1024; idx += 128) {
    const int n = idx >> 5, c4 = idx & 31;
    float4 v = F4(&x[(n0+n)*128 + c4*4]);
    xT[(c4*4+0)*33 + n] = v.x;
    xT[(c4*4+1)*33 + n] = v.y;
    xT[(c4*4+2)*33 + n] = v.z;
    xT[(c4*4+3)*33 + n] = v.w;
  }
  __syncthreads();

  const int eg = tid & 7, hg = tid >> 3;
  const int e0 = eg*4, h0 = hg*8;
  float* const outs[3] = {dq, dk, dv};

  for (int cb = 0; cb < 3; ++cb) {
    float acc[4][8];
#pragma unroll
    for (int j = 0; j < 4; ++j)
#pragma unroll
      for (int i = 0; i < 8; ++i) acc[j][i] = 0.f;

    const float* __restrict__ wbase = winT + cb*128;
    for (int k = 0; k < 128; ++k) {
      const float4 a4 = F4(&xT[k*33 + e0]);
      const float4 w0 = F4(&wbase[k*384 + h0]);
      const float4 w1 = F4(&wbase[k*384 + h0 + 4]);
      const float av[4] = {a4.x, a4.y, a4.z, a4.w};
      const float wv[8] = {w0.x, w0.y, w0.z, w0.w, w1.x, w1.y, w1.z, w1.w};
#pragma unroll
      for (int j = 0; j < 4; ++j)
#pragma unroll
        for (int i = 0; i < 8; ++i)
          acc[j][i] = fmaf(av[j], wv[i], acc[j][i]);
    }

    const float4 blo = F4(&bin[cb*128 + h0]);
    const float4 bhi = F4(&bin[cb*128 + h0 + 4]);
    float* const op = outs[cb];
#pragma unroll
    for (int j = 0; j < 4; ++j) {
      const int row = (n0 + e0 + j)*128 + h0;
      *(float4*)&op[row]   = make_float4(acc[j][0]+blo.x, acc[j][1]+blo.y, acc[j][2]+blo.z, acc[j][3]+blo.w);
      *(float4*)&op[row+4] = make_float4(acc[j][4]+bhi.x, acc[j][5]+bhi.y, acc[j][6]+bhi.z, acc[j][7]+bhi.w);
    }
  }
}

// ---------------- per-molecule attention: O = att @ v (pre-wout) ----------------
// thread = (head h = tid>>5, query row qr = tid&31); LDS rows padded to 132.
__global__ __launch_bounds__(128) void attn_kernel(
    const float* __restrict__ dq, const float* __restrict__ dk,
    const float* __restrict__ dv, float* __restrict__ O)
{
  __shared__ float sk[32*132];
  __shared__ float sv[32*132];
  const int tid = threadIdx.x;
  const int b = blockIdx.x;

  for (int idx = tid; idx < 1024; idx += 128) {
    const int a = idx >> 5, c4 = idx & 31;
    *(float4*)&sk[a*132 + c4*4] = F4(&dk[(b*32+a)*128 + c4*4]);
    *(float4*)&sv[a*132 + c4*4] = F4(&dv[(b*32+a)*128 + c4*4]);
  }
  __syncthreads();

  const int h = tid >> 5, qr = tid & 31;
  float qreg[32];
  ld32(qreg, &dq[(b*32+qr)*128 + h*32]);

  float sc[32];
#pragma unroll
  for (int k = 0; k < 32; ++k)
    sc[k] = dot32r(&sk[k*132 + h*32], qreg) * 0.17677669529663687f;
  float mx = sc[0];
#pragma unroll
  for (int k = 1; k < 32; ++k) mx = fmaxf(mx, sc[k]);
  float se = 0.f;
#pragma unroll
  for (int k = 0; k < 32; ++k) { sc[k] = expf(sc[k] - mx); se += sc[k]; }
  const float inv = 1.f / se;

  __syncthreads();  // done reading sk; reuse it as O staging

  float od[32];
#pragma unroll
  for (int i = 0; i < 32; ++i) od[i] = 0.f;
#pragma unroll 4
  for (int k = 0; k < 32; ++k) {
    const float w = sc[k] * inv;
    const float* vr = &sv[k*132 + h*32];
#pragma unroll
    for (int i = 0; i < 32; i += 4) {
      float4 v = F4(&vr[i]);
      od[i]   = fmaf(w, v.x, od[i]);
      od[i+1] = fmaf(w, v.y, od[i+1]);
      od[i+2] = fmaf(w, v.z, od[i+2]);
      od[i+3] = fmaf(w, v.w, od[i+3]);
    }
  }
#pragma unroll
  for (int i = 0; i < 32; i += 4)
    *(float4*)&sk[qr*132 + h*32 + i] = make_float4(od[i], od[i+1], od[i+2], od[i+3]);
  __syncthreads();

  for (int idx = tid; idx < 1024; idx += 128) {
    const int a = idx >> 5, c4 = idx & 31;
    *(float4*)&O[(b*32+a)*128 + c4*4] = F4(&sk[a*132 + c4*4]);
  }
}

// ---------------- attended = O @ woutT + bout ----------------
__global__ __launch_bounds__(128) void attout_kernel(
    const float* __restrict__ O, const float* __restrict__ woutT,
    const float* __restrict__ bout, float* __restrict__ att)
{
  __shared__ float xT[128*33];
  const int tid = threadIdx.x;
  const int n0 = blockIdx.x * 32;
  for (int idx = tid; idx < 1024; idx += 128) {
    const int n = idx >> 5, c4 = idx & 31;
    float4 v = F4(&O[(n0+n)*128 + c4*4]);
    xT[(c4*4+0)*33 + n] = v.x;
    xT[(c4*4+1)*33 + n] = v.y;
    xT[(c4*4+2)*33 + n] = v.z;
    xT[(c4*4+3)*33 + n] = v.w;
  }
  __syncthreads();

  const int eg = tid & 7, hg = tid >> 3;
  const int e0 = eg*4, h0 = hg*8;

  float acc[4][8];
#pragma unroll
  for (int j = 0; j < 4; ++j)
#pragma unroll
    for (int i = 0; i < 8; ++i) acc[j][i] = 0.f;

  for (int k = 0; k < 128; ++k) {
    const float4 a4 = F4(&xT[k*33 + e0]);
    const float4 w0 = F4(&woutT[k*128 + h0]);
    const float4 w1 = F4(&woutT[k*128 + h0 + 4]);
    const float av[4] = {a4.x, a4.y, a4.z, a4.w};
    const float wv[8] = {w0.x, w0.y, w0.z, w0.w, w1.x, w1.y, w1.z, w1.w};
#pragma unroll
    for (int j = 0; j < 4; ++j)
#pragma unroll
      for (int i = 0; i < 8; ++i)
        acc[j][i] = fmaf(av[j], wv[i], acc[j][i]);
  }

  const float4 blo = F4(&bout[h0]);
  const float4 bhi = F4(&bout[h0+4]);
#pragma unroll
  for (int j = 0; j < 4; ++j) {
    const int row = (n0 + e0 + j)*128 + h0;
    *(float4*)&att[row]   = make_float4(acc[j][0]+blo.x, acc[j][1]+blo.y, acc[j][2]+blo.z, acc[j][3]+blo.w);
    *(float4*)&att[row+4] = make_float4(acc[j][4]+bhi.x, acc[j][5]+bhi.y, acc[j][6]+bhi.z, acc[j][7]+bhi.w);
  }
}

// ---------------- per-molecule pooling + proj ----------------
__global__ __launch_bounds__(128) void pool_kernel(
    const float* __restrict__ att, const float* __restrict__ x,
    const float* __restrict__ pW, const float* __restrict__ pb,
    float* __restrict__ expl, float* __restrict__ lrn)
{
  __shared__ float satt[32*132];
  __shared__ float sx[32*132];
  __shared__ float aw_l[32];
  __shared__ float spool[512];
  const int tid = threadIdx.x;
  const int b = blockIdx.x;

  for (int idx = tid; idx < 1024; idx += 128) {
    const int a = idx >> 5, c4 = idx & 31;
    *(float4*)&satt[a*132 + c4*4] = F4(&att[(b*32+a)*128 + c4*4]);
    *(float4*)&sx[a*132 + c4*4]   = F4(&x[(b*32+a)*128 + c4*4]);
  }
  __syncthreads();

  { // aw logits
    const int a = tid >> 2, q4 = tid & 3;
    float sp = 0.f;
#pragma unroll
    for (int i = 0; i < 32; ++i)
      sp = fmaf(satt[a*132 + q4*32 + i], sx[a*132 + q4*32 + i], sp);
    sp += __shfl_xor(sp, 1);
    sp += __shfl_xor(sp, 2);
    if (q4 == 0) aw_l[a] = sp;
  }
  __syncthreads();

  { // pooling per column
    float awr[32];
    float mxl = aw_l[0];
#pragma unroll
    for (int a = 1; a < 32; ++a) mxl = fmaxf(mxl, aw_l[a]);
    float se = 0.f;
#pragma unroll
    for (int a = 0; a < 32; ++a) { awr[a] = expf(aw_l[a] - mxl); se += awr[a]; }
    const float inv = 1.f / se;
    const int c = tid;
    float mx = -3.4e38f, sm = 0.f, wm = 0.f, ex = 0.f;
#pragma unroll
    for (int a = 0; a < 32; ++a) {
      const float v = satt[a*132 + c];
      mx = fmaxf(mx, v);
      sm += v;
      wm = fmaf(v, awr[a], wm);
      ex += sx[a*132 + c];
    }
    wm *= inv;
    const float mean = sm * 0.03125f;
    float s2 = 0.f;
#pragma unroll
    for (int a = 0; a < 32; ++a) {
      const float d = satt[a*132 + c] - mean;
      s2 = fmaf(d, d, s2);
    }
    const float stdp = sqrtf(s2 * (1.f/31.f));
    expl[b*128 + c] = ex * 0.03125f;
    spool[c]       = wm;
    spool[128 + c] = mx;
    spool[256 + c] = mean;
    spool[384 + c] = stdp;
  }
  __syncthreads();

  if (tid < 64) {
    const int k = tid >> 4, qq = tid & 15;
    const float* pk = pW + k*2048;
    float s = pb[k*16 + qq];
    for (int h2 = 0; h2 < 128; ++h2)
      s = fmaf(spool[k*128 + h2], pk[h2*16 + qq], s);
    lrn[b*64 + tid] = s;
  }
}

// ---------------- per-(property, molecule) gated MLP heads ----------------
__global__ __launch_bounds__(64) void head_kernel(
    const float* __restrict__ molf, const float* __restrict__ lrn,
    const float* __restrict__ expl,
    const float* __restrict__ mol_gate, const float* __restrict__ lrn_gate,
    const float* __restrict__ meW1, const float* __restrict__ meb1,
    const float* __restrict__ meW2, const float* __restrict__ meb2,
    const float* __restrict__ leW1, const float* __restrict__ leb1,
    const float* __restrict__ leW2, const float* __restrict__ leb2,
    const float* __restrict__ fW1, const float* __restrict__ fb1,
    const float* __restrict__ fW2, const float* __restrict__ fb2,
    const float* __restrict__ hW1, const float* __restrict__ hb1,
    const float* __restrict__ hW2, const float* __restrict__ hb2,
    float* __restrict__ out)
{
  const int b = blockIdx.x, p = blockIdx.y, t = threadIdx.x;
  __shared__ float sgm[200];
  __shared__ float sgl[64];
  __shared__ float sA[64];
  __shared__ float sB[64];
  __shared__ float scomb[256];
  __shared__ float sf1[128];
  __shared__ float sf2[64];

  for (int m = t; m < 200; m += 64)
    sgm[m] = molf[b*200 + m] * sigmoidf_(mol_gate[p*200 + m]);
  sgl[t] = lrn[b*64 + t] * sigmoidf_(lrn_gate[p*64 + t]);
  scomb[t]      = expl[b*128 + t];
  scomb[64 + t] = expl[b*128 + 64 + t];
  __syncthreads();

  {
    float s = meb1[p*64 + t];
    const float* w = meW1 + p*12800;
    for (int m = 0; m < 200; ++m) s = fmaf(sgm[m], w[m*64 + t], s);
    sA[t] = fmaxf(s, 0.f);
    float s2 = leb1[p*64 + t];
    const float* w2 = leW1 + p*4096;
#pragma unroll 8
    for (int m = 0; m < 64; ++m) s2 = fmaf(sgl[m], w2[m*64 + t], s2);
    sB[t] = fmaxf(s2, 0.f);
  }
  __syncthreads();
  {
    float s = meb2[p*64 + t];
    const float* w = meW2 + p*4096;
#pragma unroll 8
    for (int h = 0; h < 64; ++h) s = fmaf(sA[h], w[h*64 + t], s);
    scomb[128 + t] = s;
    float s2 = leb2[p*64 + t];
    const float* w2 = leW2 + p*4096;
#pragma unroll 8
    for (int h = 0; h < 64; ++h) s2 = fmaf(sB[h], w2[h*64 + t], s2);
    scomb[192 + t] = s2;
  }
  __syncthreads();
  {
    const float* w = fW1 + p*32768;
    float s0 = fb1[p*128 + t], s1 = fb1[p*128 + 64 + t];
    for (int c = 0; c < 256; ++c) {
      const float v = scomb[c];
      s0 = fmaf(v, w[c*128 + t], s0);
      s1 = fmaf(v, w[c*128 + 64 + t], s1);
    }
    sf1[t]      = fmaxf(s0, 0.f);
    sf1[64 + t] = fmaxf(s1, 0.f);
  }
  __syncthreads();
  {
    float s = fb2[p*64 + t];
    const float* w = fW2 + p*8192;
    for (int h = 0; h < 128; ++h) s = fmaf(sf1[h], w[h*64 + t], s);
    sf2[t] = s;
  }
  __syncthreads();
  float val = 0.f;
  if (t < 32) {
    float s = hb1[p*32 + t];
    const float* w = hW1 + p*2048;
#pragma unroll 8
    for (int h = 0; h < 64; ++h) s = fmaf(sf2[h], w[h*32 + t], s);
    val = fmaxf(s, 0.f) * hW2[p*32 + t];
  }
#pragma unroll
  for (int o = 1; o < 32; o <<= 1) val += __shfl_xor(val, o);
  if (t == 0) out[p*1024 + b] = val + hb2[p];
}

extern "C" void kernel_launch(void* const* d_in, const int* in_sizes, int n_in,
                              void* d_out, int out_size, void* d_ws, size_t ws_size,
                              hipStream_t stream) {
  const float* x_atoms    = (const float*)d_in[0];
  const float* pos        = (const float*)d_in[1];
  const float* molf       = (const float*)d_in[3];
  const float* emb_W      = (const float*)d_in[4];
  const float* emb_b      = (const float*)d_in[5];
  const float* mp_W1      = (const float*)d_in[6];
  const float* mp_b1      = (const float*)d_in[7];
  const float* mp_W2      = (const float*)d_in[8];
  const float* mp_b2      = (const float*)d_in[9];
  const float* ln_g       = (const float*)d_in[10];
  const float* ln_b       = (const float*)d_in[11];
  const float* attn_in_w  = (const float*)d_in[12];
  const float* attn_in_b  = (const float*)d_in[13];
  const float* attn_out_w = (const float*)d_in[14];
  const float* attn_out_b = (const float*)d_in[15];
  const float* pool_W     = (const float*)d_in[16];
  const float* pool_b     = (const float*)d_in[17];
  const float* mol_gate   = (const float*)d_in[18];
  const float* lrn_gate   = (const float*)d_in[19];
  const float* meW1       = (const float*)d_in[20];
  const float* meb1       = (const float*)d_in[21];
  const float* meW2       = (const float*)d_in[22];
  const float* meb2       = (const float*)d_in[23];
  const float* leW1       = (const float*)d_in[24];
  const float* leb1       = (const float*)d_in[25];
  const float* leW2       = (const float*)d_in[26];
  const float* leb2       = (const float*)d_in[27];
  const float* fW1        = (const float*)d_in[28];
  const float* fb1        = (const float*)d_in[29];
  const float* fW2        = (const float*)d_in[30];
  const float* fb2        = (const float*)d_in[31];
  const float* hW1        = (const float*)d_in[32];
  const float* hb1        = (const float*)d_in[33];
  const float* hW2        = (const float*)d_in[34];
  const float* hb2        = (const float*)d_in[35];
  const int*   ei         = (const int*)d_in[36];

  float* ws      = (float*)d_ws;
  float* x       = ws;                       // NN*128
  float* P       = x + (size_t)NN*128;       // NN*128
  float* Q       = P + (size_t)NN*128;       // NN*128
  float* csr_df  = Q + (size_t)NN*128;       // NE*3
  int*   csr_src = (int*)(csr_df + (size_t)NE*3); // NE
  int*   cnt_i   = csr_src + NE;             // NN
  int*   csr_off = cnt_i + NN;               // NN+1
  int*   cur     = csr_off + NN + 1;         // NN
  float* lrn     = (float*)(cur + NN);       // NB*64
  float* expl    = lrn + NB*64;              // NB*128
  float* dv      = expl + NB*128;            // NN*128
  float* winT    = dv + (size_t)NN*128;      // 128*384
  float* woutT   = winT + 128*384;           // 128*128

  // aliases (mol path runs after the layer loop, P/Q free)
  float* dq  = P;
  float* dk  = Q;
  float* O   = Q;   // attn reads dk rows into LDS before overwriting same rows
  float* att = P;   // dq dead after attn

  hipMemsetAsync(cnt_i, 0, (size_t)NN*sizeof(int), stream);

  embed_kernel<<<NN, 128, 0, stream>>>(x_atoms, emb_W, emb_b, x);
  hist_kernel<<<NE/256, 256, 0, stream>>>(ei, cnt_i);
  scan_kernel<<<1, 1024, 0, stream>>>(cnt_i, csr_off, cur);
  scatter_kernel<<<NE/256, 256, 0, stream>>>(pos, ei, cur, csr_src, csr_df);
  transpose_kernel<<<dim3(4, 12), 256, 0, stream>>>(attn_in_w, winT, 384, 128);
  transpose_kernel<<<dim3(4, 4), 256, 0, stream>>>(attn_out_w, woutT, 128, 128);

  for (int l = 0; l < 3; ++l) {
    const float* W1l = mp_W1 + (size_t)l*259*128;
    pq_kernel<<<NN/32, 128, 0, stream>>>(x, W1l, mp_b1 + l*128, P, Q);
    agg_kernel<<<NN/4, 256, 0, stream>>>(P, Q, csr_off, csr_src, csr_df, W1l);
    gemm_ln_kernel<<<NN/32, 128, 0, stream>>>(P, mp_W2 + (size_t)l*128*128, mp_b2 + l*128,
                                              csr_off, ln_g + l*128, ln_b + l*128, x);
  }

  qkv_kernel<<<NN/32, 128, 0, stream>>>(x, winT, attn_in_b, dq, dk, dv);
  attn_kernel<<<NB, 128, 0, stream>>>(dq, dk, dv, O);
  attout_kernel<<<NN/32, 128, 0, stream>>>(O, woutT, attn_out_b, att);
  pool_kernel<<<NB, 128, 0, stream>>>(att, x, pool_W, pool_b, expl, lrn);
  head_kernel<<<dim3(NB, 4), 64, 0, stream>>>(molf, lrn, expl, mol_gate, lrn_gate,
      meW1, meb1, meW2, meb2, leW1, leb1, leW2, leb2,
      fW1, fb1, fW2, fb2, hW1, hb1, hW2, hb2, (float*)d_out);
}

// Round 4
// 666.046 us; speedup vs baseline: 12.2041x; 1.0208x over previous
//
#include <hip/hip_runtime.h>

#define NE 524288
#define NN 32768
#define NB 1024

#define F4(p) (*(const float4*)(p))

__device__ __forceinline__ float sigmoidf_(float v) { return 1.f / (1.f + expf(-v)); }

__device__ __forceinline__ void ld32(float* xr, const float* p) {
#pragma unroll
  for (int i = 0; i < 32; i += 4) {
    float4 v = F4(&p[i]);
    xr[i] = v.x; xr[i+1] = v.y; xr[i+2] = v.z; xr[i+3] = v.w;
  }
}

__device__ __forceinline__ float dot32r(const float* __restrict__ w, const float* xr) {
  float s = 0.f;
#pragma unroll
  for (int i = 0; i < 32; i += 4) {
    float4 ww = F4(&w[i]);
    s = fmaf(xr[i],   ww.x, s);
    s = fmaf(xr[i+1], ww.y, s);
    s = fmaf(xr[i+2], ww.z, s);
    s = fmaf(xr[i+3], ww.w, s);
  }
  return s;
}

// ---------------- embedding ----------------
__global__ __launch_bounds__(128) void embed_kernel(
    const float* __restrict__ xa, const float* __restrict__ W,
    const float* __restrict__ b, float* __restrict__ x)
{
  __shared__ float a[64];
  const int n = blockIdx.x, t = threadIdx.x;
  if (t < 64) a[t] = xa[n*64 + t];
  __syncthreads();
  float s = b[t];
#pragma unroll 8
  for (int f = 0; f < 64; ++f) s = fmaf(a[f], W[f*128 + t], s);
  x[n*128 + t] = s;
}

// ---------------- CSR build ----------------
__global__ __launch_bounds__(256) void hist_kernel(const int* __restrict__ ei, int* __restrict__ cnt) {
  const int e = blockIdx.x*256 + threadIdx.x;
  atomicAdd(&cnt[ei[NE + e]], 1);
}

__global__ __launch_bounds__(1024) void scan_kernel(
    const int* __restrict__ cnt, int* __restrict__ off, int* __restrict__ cur)
{
  __shared__ int wsum[16];
  const int t = threadIdx.x;
  int local[32];
  const int base = t*32;
  int s = 0;
#pragma unroll
  for (int i = 0; i < 32; ++i) { local[i] = cnt[base+i]; s += local[i]; }
  int pre = s;
  const int lane = t & 63;
#pragma unroll
  for (int o = 1; o < 64; o <<= 1) { int v = __shfl_up(pre, o); if (lane >= o) pre += v; }
  if (lane == 63) wsum[t >> 6] = pre;
  __syncthreads();
  if (t == 0) { int a = 0; for (int w = 0; w < 16; ++w) { int v = wsum[w]; wsum[w] = a; a += v; } }
  __syncthreads();
  int excl = wsum[t >> 6] + pre - s;
#pragma unroll
  for (int i = 0; i < 32; ++i) { off[base+i] = excl; cur[base+i] = excl; excl += local[i]; }
  if (t == 1023) off[NN] = excl;
}

__global__ __launch_bounds__(256) void scatter_kernel(
    const float* __restrict__ pos, const int* __restrict__ ei,
    int* __restrict__ cur, int* __restrict__ csr_src, float* __restrict__ csr_df)
{
  const int e = blockIdx.x*256 + threadIdx.x;
  const int s = ei[e];
  const int d = ei[NE + e];
  float dx = pos[d*3+0] - pos[s*3+0];
  float dy = pos[d*3+1] - pos[s*3+1];
  float dz = pos[d*3+2] - pos[s*3+2];
  float dist = sqrtf(dx*dx + dy*dy + dz*dz + 1e-12f);
  const int slot = atomicAdd(&cur[d], 1);
  csr_src[slot] = s;
  csr_df[slot*3+0] = dist;
  csr_df[slot*3+1] = 1.f/(1.f + dist);
  csr_df[slot*3+2] = expf(-dist);
}

// ---------------- 32x32 tile transpose ----------------
__global__ __launch_bounds__(256) void transpose_kernel(
    const float* __restrict__ in, float* __restrict__ out, int rows, int cols)
{
  __shared__ float tile[32][33];
  const int c0 = blockIdx.x*32, r0 = blockIdx.y*32;
  const int t = threadIdx.x;
  const int tr = t >> 5, tc = t & 31;
  for (int i = tr; i < 32; i += 8)
    tile[i][tc] = in[(r0+i)*cols + (c0+tc)];
  __syncthreads();
  for (int i = tr; i < 32; i += 8)
    out[(c0+i)*rows + (r0+tc)] = tile[tc][i];
}

// ---------------- P = x@W1a + b1 ; Q = x@W1b  (32 nodes, 256 thr, 4x4x2 tile) ----------------
__global__ __launch_bounds__(256) void pq_kernel(
    const float* __restrict__ x, const float* __restrict__ W1,
    const float* __restrict__ b1, float* __restrict__ P, float* __restrict__ Q)
{
  __shared__ float xT[128*33];
  const int tid = threadIdx.x;
  const int n0 = blockIdx.x * 32;
  for (int idx = tid; idx < 1024; idx += 256) {
    const int n = idx >> 5, c4 = idx & 31;
    float4 v = F4(&x[(n0+n)*128 + c4*4]);
    xT[(c4*4+0)*33 + n] = v.x;
    xT[(c4*4+1)*33 + n] = v.y;
    xT[(c4*4+2)*33 + n] = v.z;
    xT[(c4*4+3)*33 + n] = v.w;
  }
  __syncthreads();

  const int eg = tid & 7, cg = tid >> 3;   // 8 node-groups x 32 col-groups
  const int e0 = eg*4, c0 = cg*4;
  const float* __restrict__ W1b = W1 + 128*128;

  float pa[4][4], qa[4][4];
#pragma unroll
  for (int j = 0; j < 4; ++j)
#pragma unroll
    for (int i = 0; i < 4; ++i) { pa[j][i] = 0.f; qa[j][i] = 0.f; }

  for (int k = 0; k < 128; ++k) {
    const float4 a4 = F4(&xT[k*33 + e0]);
    const float4 wp = F4(&W1[k*128 + c0]);
    const float4 wq = F4(&W1b[k*128 + c0]);
    const float av[4] = {a4.x, a4.y, a4.z, a4.w};
    const float pv[4] = {wp.x, wp.y, wp.z, wp.w};
    const float qv[4] = {wq.x, wq.y, wq.z, wq.w};
#pragma unroll
    for (int j = 0; j < 4; ++j)
#pragma unroll
      for (int i = 0; i < 4; ++i) {
        pa[j][i] = fmaf(av[j], pv[i], pa[j][i]);
        qa[j][i] = fmaf(av[j], qv[i], qa[j][i]);
      }
  }

  const float4 bl = F4(&b1[c0]);
#pragma unroll
  for (int j = 0; j < 4; ++j) {
    const int row = (n0 + e0 + j)*128 + c0;
    *(float4*)&P[row] = make_float4(pa[j][0]+bl.x, pa[j][1]+bl.y, pa[j][2]+bl.z, pa[j][3]+bl.w);
    *(float4*)&Q[row] = make_float4(qa[j][0], qa[j][1], qa[j][2], qa[j][3]);
  }
}

// ---------------- aggregation: P[n] <- mean_e relu(P[n]+Q[src]+df@W1c) ----------------
// 4 nodes/block, one wave per node; csr loads are wave-uniform -> HW broadcast.
__global__ __launch_bounds__(256) void agg_kernel(
    float* __restrict__ P, const float* __restrict__ Q,
    const int* __restrict__ csr_off, const int* __restrict__ csr_src,
    const float* __restrict__ csr_df, const float* __restrict__ W1)
{
  const int tid = threadIdx.x;
  const int node = blockIdx.x*4 + (tid >> 6);
  const int lane = tid & 63;
  const int c0 = lane*2;
  const int off0 = csr_off[node], off1 = csr_off[node+1];

  const float* __restrict__ w1c = W1 + 256*128;
  const float w00 = w1c[c0],       w01 = w1c[c0+1];
  const float w10 = w1c[128+c0],   w11 = w1c[128+c0+1];
  const float w20 = w1c[256+c0],   w21 = w1c[256+c0+1];
  const float2 p = *(const float2*)&P[node*128 + c0];

  float a0 = 0.f, a1 = 0.f;
  int e = off0;
  for (; e + 4 <= off1; e += 4) {
#pragma unroll
    for (int j = 0; j < 4; ++j) {
      const int src = csr_src[e+j];
      const float d0 = csr_df[(e+j)*3+0];
      const float d1 = csr_df[(e+j)*3+1];
      const float d2 = csr_df[(e+j)*3+2];
      const float2 q = *(const float2*)&Q[src*128 + c0];
      float h0 = p.x + q.x;
      h0 = fmaf(d0, w00, h0); h0 = fmaf(d1, w10, h0); h0 = fmaf(d2, w20, h0);
      float h1 = p.y + q.y;
      h1 = fmaf(d0, w01, h1); h1 = fmaf(d1, w11, h1); h1 = fmaf(d2, w21, h1);
      a0 += fmaxf(h0, 0.f);
      a1 += fmaxf(h1, 0.f);
    }
  }
  for (; e < off1; ++e) {
    const int src = csr_src[e];
    const float d0 = csr_df[e*3+0];
    const float d1 = csr_df[e*3+1];
    const float d2 = csr_df[e*3+2];
    const float2 q = *(const float2*)&Q[src*128 + c0];
    float h0 = p.x + q.x;
    h0 = fmaf(d0, w00, h0); h0 = fmaf(d1, w10, h0); h0 = fmaf(d2, w20, h0);
    float h1 = p.y + q.y;
    h1 = fmaf(d0, w01, h1); h1 = fmaf(d1, w11, h1); h1 = fmaf(d2, w21, h1);
    a0 += fmaxf(h0, 0.f);
    a1 += fmaxf(h1, 0.f);
  }
  const int deg = off1 - off0;
  const float rc = deg > 0 ? 1.f/(float)deg : 1.f;
  *(float2*)&P[node*128 + c0] = make_float2(a0*rc, a1*rc);
}

// ---------------- x <- LN(A@W2 + (deg>0)*b2 + x)  (256 thr, 4x4 tile) ----------------
__global__ __launch_bounds__(256) void gemm_ln_kernel(
    const float* __restrict__ A, const float* __restrict__ W2,
    const float* __restrict__ b2, const int* __restrict__ csr_off,
    const float* __restrict__ g, const float* __restrict__ bb,
    float* __restrict__ x)
{
  __shared__ float smem[128*33];  // xT stage, then out tile [32][132] (4224 floats both)
  const int tid = threadIdx.x;
  const int n0 = blockIdx.x * 32;
  for (int idx = tid; idx < 1024; idx += 256) {
    const int n = idx >> 5, c4 = idx & 31;
    float4 v = F4(&A[(n0+n)*128 + c4*4]);
    smem[(c4*4+0)*33 + n] = v.x;
    smem[(c4*4+1)*33 + n] = v.y;
    smem[(c4*4+2)*33 + n] = v.z;
    smem[(c4*4+3)*33 + n] = v.w;
  }
  __syncthreads();

  const int eg = tid & 7, cg = tid >> 3;
  const int e0 = eg*4, c0 = cg*4;

  float acc[4][4];
#pragma unroll
  for (int j = 0; j < 4; ++j)
#pragma unroll
    for (int i = 0; i < 4; ++i) acc[j][i] = 0.f;

  for (int k = 0; k < 128; ++k) {
    const float4 a4 = F4(&smem[k*33 + e0]);
    const float4 w = F4(&W2[k*128 + c0]);
    const float av[4] = {a4.x, a4.y, a4.z, a4.w};
    const float wv[4] = {w.x, w.y, w.z, w.w};
#pragma unroll
    for (int j = 0; j < 4; ++j)
#pragma unroll
      for (int i = 0; i < 4; ++i)
        acc[j][i] = fmaf(av[j], wv[i], acc[j][i]);
  }
  __syncthreads();

  const float4 bl = F4(&b2[c0]);
#pragma unroll
  for (int j = 0; j < 4; ++j) {
    const int n = n0 + e0 + j;
    const float s = (csr_off[n+1] > csr_off[n]) ? 1.f : 0.f;
    const float4 x0 = F4(&x[n*128 + c0]);
    float4 o;
    o.x = acc[j][0] + s*bl.x + x0.x;
    o.y = acc[j][1] + s*bl.y + x0.y;
    o.z = acc[j][2] + s*bl.z + x0.z;
    o.w = acc[j][3] + s*bl.w + x0.w;
    *(float4*)&smem[(e0+j)*132 + c0] = o;
  }
  __syncthreads();

  // layernorm: 8 threads per row, 16 cols each
  const int a = tid >> 3, q8 = tid & 7;
  const float* row = &smem[a*132 + q8*16];
  float s1 = 0.f, s2 = 0.f;
#pragma unroll
  for (int i = 0; i < 16; ++i) { const float v = row[i]; s1 += v; s2 = fmaf(v, v, s2); }
  s1 += __shfl_xor(s1, 1); s2 += __shfl_xor(s2, 1);
  s1 += __shfl_xor(s1, 2); s2 += __shfl_xor(s2, 2);
  s1 += __shfl_xor(s1, 4); s2 += __shfl_xor(s2, 4);
  const float mu = s1 * (1.f/128.f);
  const float var = s2 * (1.f/128.f) - mu*mu;
  const float rstd = rsqrtf(var + 1e-5f);
#pragma unroll
  for (int i = 0; i < 16; i += 4) {
    const float4 gg = F4(&g[q8*16 + i]);
    const float4 bv = F4(&bb[q8*16 + i]);
    float4 o;
    o.x = (row[i]   - mu)*rstd*gg.x + bv.x;
    o.y = (row[i+1] - mu)*rstd*gg.y + bv.y;
    o.z = (row[i+2] - mu)*rstd*gg.z + bv.z;
    o.w = (row[i+3] - mu)*rstd*gg.w + bv.w;
    *(float4*)&x[(n0+a)*128 + q8*16 + i] = o;
  }
}

// ---------------- qkv = x @ winT + bin  (256 thr, 3 chunks of 4x4) ----------------
__global__ __launch_bounds__(256) void qkv_kernel(
    const float* __restrict__ x, const float* __restrict__ winT,
    const float* __restrict__ bin,
    float* __restrict__ dq, float* __restrict__ dk, float* __restrict__ dv)
{
  __shared__ float xT[128*33];
  const int tid = threadIdx.x;
  const int n0 = blockIdx.x * 32;
  for (int idx = tid; idx < 1024; idx += 256) {
    const int n = idx >> 5, c4 = idx & 31;
    float4 v = F4(&x[(n0+n)*128 + c4*4]);
    xT[(c4*4+0)*33 + n] = v.x;
    xT[(c4*4+1)*33 + n] = v.y;
    xT[(c4*4+2)*33 + n] = v.z;
    xT[(c4*4+3)*33 + n] = v.w;
  }
  __syncthreads();

  const int eg = tid & 7, cg = tid >> 3;
  const int e0 = eg*4, c0 = cg*4;
  float* const outs[3] = {dq, dk, dv};

  for (int cb = 0; cb < 3; ++cb) {
    float acc[4][4];
#pragma unroll
    for (int j = 0; j < 4; ++j)
#pragma unroll
      for (int i = 0; i < 4; ++i) acc[j][i] = 0.f;

    const float* __restrict__ wbase = winT + cb*128;
    for (int k = 0; k < 128; ++k) {
      const float4 a4 = F4(&xT[k*33 + e0]);
      const float4 w = F4(&wbase[k*384 + c0]);
      const float av[4] = {a4.x, a4.y, a4.z, a4.w};
      const float wv[4] = {w.x, w.y, w.z, w.w};
#pragma unroll
      for (int j = 0; j < 4; ++j)
#pragma unroll
        for (int i = 0; i < 4; ++i)
          acc[j][i] = fmaf(av[j], wv[i], acc[j][i]);
    }

    const float4 bl = F4(&bin[cb*128 + c0]);
    float* const op = outs[cb];
#pragma unroll
    for (int j = 0; j < 4; ++j) {
      const int row = (n0 + e0 + j)*128 + c0;
      *(float4*)&op[row] = make_float4(acc[j][0]+bl.x, acc[j][1]+bl.y, acc[j][2]+bl.z, acc[j][3]+bl.w);
    }
  }
}

// ---------------- per-molecule attention: O = softmax(qk)v ----------------
__global__ __launch_bounds__(128) void attn_kernel(
    const float* __restrict__ dq, const float* __restrict__ dk,
    const float* __restrict__ dv, float* __restrict__ O)
{
  __shared__ float sk[32*132];
  __shared__ float sv[32*132];
  const int tid = threadIdx.x;
  const int b = blockIdx.x;

  for (int idx = tid; idx < 1024; idx += 128) {
    const int a = idx >> 5, c4 = idx & 31;
    *(float4*)&sk[a*132 + c4*4] = F4(&dk[(b*32+a)*128 + c4*4]);
    *(float4*)&sv[a*132 + c4*4] = F4(&dv[(b*32+a)*128 + c4*4]);
  }
  __syncthreads();

  const int h = tid >> 5, qr = tid & 31;
  float qreg[32];
  ld32(qreg, &dq[(b*32+qr)*128 + h*32]);

  float sc[32];
#pragma unroll
  for (int k = 0; k < 32; ++k)
    sc[k] = dot32r(&sk[k*132 + h*32], qreg) * 0.17677669529663687f;
  float mx = sc[0];
#pragma unroll
  for (int k = 1; k < 32; ++k) mx = fmaxf(mx, sc[k]);
  float se = 0.f;
#pragma unroll
  for (int k = 0; k < 32; ++k) { sc[k] = expf(sc[k] - mx); se += sc[k]; }
  const float inv = 1.f / se;

  __syncthreads();  // done reading sk; reuse as O staging

  float od[32];
#pragma unroll
  for (int i = 0; i < 32; ++i) od[i] = 0.f;
#pragma unroll 4
  for (int k = 0; k < 32; ++k) {
    const float w = sc[k] * inv;
    const float* vr = &sv[k*132 + h*32];
#pragma unroll
    for (int i = 0; i < 32; i += 4) {
      float4 v = F4(&vr[i]);
      od[i]   = fmaf(w, v.x, od[i]);
      od[i+1] = fmaf(w, v.y, od[i+1]);
      od[i+2] = fmaf(w, v.z, od[i+2]);
      od[i+3] = fmaf(w, v.w, od[i+3]);
    }
  }
#pragma unroll
  for (int i = 0; i < 32; i += 4)
    *(float4*)&sk[qr*132 + h*32 + i] = make_float4(od[i], od[i+1], od[i+2], od[i+3]);
  __syncthreads();

  for (int idx = tid; idx < 1024; idx += 128) {
    const int a = idx >> 5, c4 = idx & 31;
    *(float4*)&O[(b*32+a)*128 + c4*4] = F4(&sk[a*132 + c4*4]);
  }
}

// ---------------- attended = O @ woutT + bout, fused with pooling + proj ----------------
// one block = one molecule (32 nodes), 256 threads.
__global__ __launch_bounds__(256) void attout_pool_kernel(
    const float* __restrict__ O, const float* __restrict__ woutT,
    const float* __restrict__ bout, const float* __restrict__ x,
    const float* __restrict__ pW, const float* __restrict__ pb,
    float* __restrict__ expl, float* __restrict__ lrn)
{
  __shared__ float OT[4224];   // [128][33] stage; aliased as satt [32][132] after GEMM
  __shared__ float sx[4224];   // [32][132]
  __shared__ float aw_l[32];
  __shared__ float spool[512];
  const int tid = threadIdx.x;
  const int b = blockIdx.x;
  const int n0 = b * 32;

  for (int idx = tid; idx < 1024; idx += 256) {
    const int n = idx >> 5, c4 = idx & 31;
    float4 v = F4(&O[(n0+n)*128 + c4*4]);
    OT[(c4*4+0)*33 + n] = v.x;
    OT[(c4*4+1)*33 + n] = v.y;
    OT[(c4*4+2)*33 + n] = v.z;
    OT[(c4*4+3)*33 + n] = v.w;
    *(float4*)&sx[n*132 + c4*4] = F4(&x[(n0+n)*128 + c4*4]);
  }
  __syncthreads();

  const int eg = tid & 7, cg = tid >> 3;
  const int e0 = eg*4, c0 = cg*4;

  float acc[4][4];
#pragma unroll
  for (int j = 0; j < 4; ++j)
#pragma unroll
    for (int i = 0; i < 4; ++i) acc[j][i] = 0.f;

  for (int k = 0; k < 128; ++k) {
    const float4 a4 = F4(&OT[k*33 + e0]);
    const float4 w = F4(&woutT[k*128 + c0]);
    const float av[4] = {a4.x, a4.y, a4.z, a4.w};
    const float wv[4] = {w.x, w.y, w.z, w.w};
#pragma unroll
    for (int j = 0; j < 4; ++j)
#pragma unroll
      for (int i = 0; i < 4; ++i)
        acc[j][i] = fmaf(av[j], wv[i], acc[j][i]);
  }
  __syncthreads();  // done reading OT -> alias as satt

  float* satt = OT;
  const float4 bl = F4(&bout[c0]);
#pragma unroll
  for (int j = 0; j < 4; ++j) {
    float4 o;
    o.x = acc[j][0] + bl.x;
    o.y = acc[j][1] + bl.y;
    o.z = acc[j][2] + bl.z;
    o.w = acc[j][3] + bl.w;
    *(float4*)&satt[(e0+j)*132 + c0] = o;
  }
  __syncthreads();

  { // aw logits: 8 threads/row
    const int a = tid >> 3, q8 = tid & 7;
    float sp = 0.f;
#pragma unroll
    for (int i = 0; i < 16; ++i)
      sp = fmaf(satt[a*132 + q8*16 + i], sx[a*132 + q8*16 + i], sp);
    sp += __shfl_xor(sp, 1);
    sp += __shfl_xor(sp, 2);
    sp += __shfl_xor(sp, 4);
    if (q8 == 0) aw_l[a] = sp;
  }
  __syncthreads();

  if (tid < 128) { // pooling per column
    float awr[32];
    float mxl = aw_l[0];
#pragma unroll
    for (int a = 1; a < 32; ++a) mxl = fmaxf(mxl, aw_l[a]);
    float se = 0.f;
#pragma unroll
    for (int a = 0; a < 32; ++a) { awr[a] = expf(aw_l[a] - mxl); se += awr[a]; }
    const float inv = 1.f / se;
    const int c = tid;
    float mx = -3.4e38f, sm = 0.f, wm = 0.f, ex = 0.f;
#pragma unroll
    for (int a = 0; a < 32; ++a) {
      const float v = satt[a*132 + c];
      mx = fmaxf(mx, v);
      sm += v;
      wm = fmaf(v, awr[a], wm);
      ex += sx[a*132 + c];
    }
    wm *= inv;
    const float mean = sm * 0.03125f;
    float s2 = 0.f;
#pragma unroll
    for (int a = 0; a < 32; ++a) {
      const float d = satt[a*132 + c] - mean;
      s2 = fmaf(d, d, s2);
    }
    const float stdp = sqrtf(s2 * (1.f/31.f));  // ddof=1
    expl[b*128 + c] = ex * 0.03125f;
    spool[c]       = wm;
    spool[128 + c] = mx;
    spool[256 + c] = mean;
    spool[384 + c] = stdp;
  }
  __syncthreads();

  if (tid < 64) { // proj -> learned
    const int k = tid >> 4, qq = tid & 15;
    const float* pk = pW + k*2048;
    float s = pb[k*16 + qq];
    for (int h2 = 0; h2 < 128; ++h2)
      s = fmaf(spool[k*128 + h2], pk[h2*16 + qq], s);
    lrn[b*64 + tid] = s;
  }
}

// ---------------- per-(property, molecule) gated MLP heads ----------------
__global__ __launch_bounds__(64) void head_kernel(
    const float* __restrict__ molf, const float* __restrict__ lrn,
    const float* __restrict__ expl,
    const float* __restrict__ mol_gate, const float* __restrict__ lrn_gate,
    const float* __restrict__ meW1, const float* __restrict__ meb1,
    const float* __restrict__ meW2, const float* __restrict__ meb2,
    const float* __restrict__ leW1, const float* __restrict__ leb1,
    const float* __restrict__ leW2, const float* __restrict__ leb2,
    const float* __restrict__ fW1, const float* __restrict__ fb1,
    const float* __restrict__ fW2, const float* __restrict__ fb2,
    const float* __restrict__ hW1, const float* __restrict__ hb1,
    const float* __restrict__ hW2, const float* __restrict__ hb2,
    float* __restrict__ out)
{
  const int b = blockIdx.x, p = blockIdx.y, t = threadIdx.x;
  __shared__ float sgm[200];
  __shared__ float sgl[64];
  __shared__ float sA[64];
  __shared__ float sB[64];
  __shared__ float scomb[256];
  __shared__ float sf1[128];
  __shared__ float sf2[64];

  for (int m = t; m < 200; m += 64)
    sgm[m] = molf[b*200 + m] * sigmoidf_(mol_gate[p*200 + m]);
  sgl[t] = lrn[b*64 + t] * sigmoidf_(lrn_gate[p*64 + t]);
  scomb[t]      = expl[b*128 + t];
  scomb[64 + t] = expl[b*128 + 64 + t];
  __syncthreads();

  {
    float s = meb1[p*64 + t];
    const float* w = meW1 + p*12800;
    for (int m = 0; m < 200; ++m) s = fmaf(sgm[m], w[m*64 + t], s);
    sA[t] = fmaxf(s, 0.f);
    float s2 = leb1[p*64 + t];
    const float* w2 = leW1 + p*4096;
#pragma unroll 8
    for (int m = 0; m < 64; ++m) s2 = fmaf(sgl[m], w2[m*64 + t], s2);
    sB[t] = fmaxf(s2, 0.f);
  }
  __syncthreads();
  {
    float s = meb2[p*64 + t];
    const float* w = meW2 + p*4096;
#pragma unroll 8
    for (int h = 0; h < 64; ++h) s = fmaf(sA[h], w[h*64 + t], s);
    scomb[128 + t] = s;
    float s2 = leb2[p*64 + t];
    const float* w2 = leW2 + p*4096;
#pragma unroll 8
    for (int h = 0; h < 64; ++h) s2 = fmaf(sB[h], w2[h*64 + t], s2);
    scomb[192 + t] = s2;
  }
  __syncthreads();
  {
    const float* w = fW1 + p*32768;
    float s0 = fb1[p*128 + t], s1 = fb1[p*128 + 64 + t];
    for (int c = 0; c < 256; ++c) {
      const float v = scomb[c];
      s0 = fmaf(v, w[c*128 + t], s0);
      s1 = fmaf(v, w[c*128 + 64 + t], s1);
    }
    sf1[t]      = fmaxf(s0, 0.f);
    sf1[64 + t] = fmaxf(s1, 0.f);
  }
  __syncthreads();
  {
    float s = fb2[p*64 + t];
    const float* w = fW2 + p*8192;
    for (int h = 0; h < 128; ++h) s = fmaf(sf1[h], w[h*64 + t], s);
    sf2[t] = s;
  }
  __syncthreads();
  float val = 0.f;
  if (t < 32) {
    float s = hb1[p*32 + t];
    const float* w = hW1 + p*2048;
#pragma unroll 8
    for (int h = 0; h < 64; ++h) s = fmaf(sf2[h], w[h*32 + t], s);
    val = fmaxf(s, 0.f) * hW2[p*32 + t];
  }
#pragma unroll
  for (int o = 1; o < 32; o <<= 1) val += __shfl_xor(val, o);
  if (t == 0) out[p*1024 + b] = val + hb2[p];
}

extern "C" void kernel_launch(void* const* d_in, const int* in_sizes, int n_in,
                              void* d_out, int out_size, void* d_ws, size_t ws_size,
                              hipStream_t stream) {
  const float* x_atoms    = (const float*)d_in[0];
  const float* pos        = (const float*)d_in[1];
  const float* molf       = (const float*)d_in[3];
  const float* emb_W      = (const float*)d_in[4];
  const float* emb_b      = (const float*)d_in[5];
  const float* mp_W1      = (const float*)d_in[6];
  const float* mp_b1      = (const float*)d_in[7];
  const float* mp_W2      = (const float*)d_in[8];
  const float* mp_b2      = (const float*)d_in[9];
  const float* ln_g       = (const float*)d_in[10];
  const float* ln_b       = (const float*)d_in[11];
  const float* attn_in_w  = (const float*)d_in[12];
  const float* attn_in_b  = (const float*)d_in[13];
  const float* attn_out_w = (const float*)d_in[14];
  const float* attn_out_b = (const float*)d_in[15];
  const float* pool_W     = (const float*)d_in[16];
  const float* pool_b     = (const float*)d_in[17];
  const float* mol_gate   = (const float*)d_in[18];
  const float* lrn_gate   = (const float*)d_in[19];
  const float* meW1       = (const float*)d_in[20];
  const float* meb1       = (const float*)d_in[21];
  const float* meW2       = (const float*)d_in[22];
  const float* meb2       = (const float*)d_in[23];
  const float* leW1       = (const float*)d_in[24];
  const float* leb1       = (const float*)d_in[25];
  const float* leW2       = (const float*)d_in[26];
  const float* leb2       = (const float*)d_in[27];
  const float* fW1        = (const float*)d_in[28];
  const float* fb1        = (const float*)d_in[29];
  const float* fW2        = (const float*)d_in[30];
  const float* fb2        = (const float*)d_in[31];
  const float* hW1        = (const float*)d_in[32];
  const float* hb1        = (const float*)d_in[33];
  const float* hW2        = (const float*)d_in[34];
  const float* hb2        = (const float*)d_in[35];
  const int*   ei         = (const int*)d_in[36];

  float* ws      = (float*)d_ws;
  float* x       = ws;                       // NN*128
  float* P       = x + (size_t)NN*128;       // NN*128
  float* Q       = P + (size_t)NN*128;       // NN*128
  float* csr_df  = Q + (size_t)NN*128;       // NE*3
  int*   csr_src = (int*)(csr_df + (size_t)NE*3); // NE
  int*   cnt_i   = csr_src + NE;             // NN
  int*   csr_off = cnt_i + NN;               // NN+1
  int*   cur     = csr_off + NN + 1;         // NN
  float* lrn     = (float*)(cur + NN);       // NB*64
  float* expl    = lrn + NB*64;              // NB*128
  float* dv      = expl + NB*128;            // NN*128
  float* winT    = dv + (size_t)NN*128;      // 128*384
  float* woutT   = winT + 128*384;           // 128*128

  // aliases (mol path runs after the layer loop, P/Q free)
  float* dq = P;
  float* dk = Q;
  float* O  = Q;   // attn reads dk rows into LDS before overwriting same rows

  hipMemsetAsync(cnt_i, 0, (size_t)NN*sizeof(int), stream);

  embed_kernel<<<NN, 128, 0, stream>>>(x_atoms, emb_W, emb_b, x);
  hist_kernel<<<NE/256, 256, 0, stream>>>(ei, cnt_i);
  scan_kernel<<<1, 1024, 0, stream>>>(cnt_i, csr_off, cur);
  scatter_kernel<<<NE/256, 256, 0, stream>>>(pos, ei, cur, csr_src, csr_df);
  transpose_kernel<<<dim3(4, 12), 256, 0, stream>>>(attn_in_w, winT, 384, 128);
  transpose_kernel<<<dim3(4, 4), 256, 0, stream>>>(attn_out_w, woutT, 128, 128);

  for (int l = 0; l < 3; ++l) {
    const float* W1l = mp_W1 + (size_t)l*259*128;
    pq_kernel<<<NN/32, 256, 0, stream>>>(x, W1l, mp_b1 + l*128, P, Q);
    agg_kernel<<<NN/4, 256, 0, stream>>>(P, Q, csr_off, csr_src, csr_df, W1l);
    gemm_ln_kernel<<<NN/32, 256, 0, stream>>>(P, mp_W2 + (size_t)l*128*128, mp_b2 + l*128,
                                              csr_off, ln_g + l*128, ln_b + l*128, x);
  }

  qkv_kernel<<<NN/32, 256, 0, stream>>>(x, winT, attn_in_b, dq, dk, dv);
  attn_kernel<<<NB, 128, 0, stream>>>(dq, dk, dv, O);
  attout_pool_kernel<<<NB, 256, 0, stream>>>(O, woutT, attn_out_b, x,
                                             pool_W, pool_b, expl, lrn);
  head_kernel<<<dim3(NB, 4), 64, 0, stream>>>(molf, lrn, expl, mol_gate, lrn_gate,
      meW1, meb1, meW2, meb2, leW1, leb1, leW2, leb2,
      fW1, fb1, fW2, fb2, hW1, hb1, hW2, hb2, (float*)d_out);
}